// Round 1
// 223.739 us; speedup vs baseline: 1.3923x; 1.3923x over previous
//
#include <hip/hip_runtime.h>
#include <hip/hip_bf16.h>
#include <stdint.h>
#include <string.h>
#include <math.h>

// Problem constants
#define B_ 8
#define N_ 512
#define C_ 384
#define HR_ 192          // H*R = 6*32
#define PH_ 16           // PAIR_HIDDEN
#define HEAD_SCALE_ 0.17677669529663687f

// Workspace layout (float offsets)
#define OFF_X   0
#define OFF_Q   (B_*N_*C_)
#define OFF_K   (OFF_Q + B_*N_*HR_)
#define OFF_A   (OFF_K + B_*N_*HR_)
#define OFF_BJ  (OFF_A + B_*N_*PH_)
#define OFF_D   (OFF_BJ + B_*N_*PH_)
#define OFF_CS  (OFF_D + B_*N_)
#define OFF_W   (OFF_CS + 2*B_)
#define OFF_FLAG (OFF_W + 700)               // int: 1 = inputs are bf16, 0 = f32
#define WS_FLOATS (OFF_W + 768)

struct VInit { float v[16]; };

__device__ __forceinline__ float cvt(ushort u) {
  union { uint32_t i; float f; } x; x.i = ((uint32_t)u) << 16; return x.f;
}
__device__ __forceinline__ float cvt(float f) { return f; }

__device__ __forceinline__ float4 ld4v(const ushort* p) {
  ushort4 u = *(const ushort4*)p;
  return make_float4(cvt(u.x), cvt(u.y), cvt(u.z), cvt(u.w));
}
__device__ __forceinline__ float4 ld4v(const float* p) { return *(const float4*)p; }

// ---------------------------------------------------------------------------
// Kernel 0: dtype detection. If Wg1 holds bf16, the low ushort of each dword
// decodes to a sane-magnitude bf16 (N(0,0.3) weights). If it holds f32, the
// low 16 bits are uniform mantissa bits (sane-decode prob ~10%). 128 dwords
// are valid to read under both layouts (512 B <= min(768, 1536) B).
// ---------------------------------------------------------------------------
__global__ void detect_kernel(const uint32_t* __restrict__ wg1, float* __restrict__ ws) {
  if (threadIdx.x == 0 && blockIdx.x == 0) {
    int cnt = 0;
    for (int i = 0; i < 128; ++i) {
      uint32_t d = wg1[i];
      float v = cvt((ushort)(d & 0xFFFFu));
      float av = fabsf(v);
      if (av == 0.0f || (av >= 9.5367431640625e-07f && av <= 32.0f)) ++cnt;
    }
    *(int*)(ws + OFF_FLAG) = (cnt >= 64) ? 1 : 0;
  }
}

// ---------------------------------------------------------------------------
// Weight tables (transposed for uniform scalar loads in score kernel)
// ---------------------------------------------------------------------------
template <typename T>
__device__ void build_tables(const T* Wg1, const T* bg1, const T* Wg2, const T* bg2,
                             const T* Wa1, const T* ba1, const T* Wa2, const T* ba2,
                             const T* apair, const T* ageom, const T* aang, const T* lsc,
                             float* ws, int tid) {
  for (int j = tid; j < 32; j += 256) {
    float* wj = ws + OFF_W + j*16;
    #pragma unroll
    for (int i = 0; i < 12; ++i) wj[i] = cvt(Wg1[i*32 + j]);
    wj[12] = cvt(bg1[j]);
    wj[13] = cvt(Wg2[j]);
    wj[14] = 0.f; wj[15] = 0.f;
  }
  for (int j = tid; j < 16; j += 256) {
    float* wj = ws + OFF_W + 512 + j*8;
    #pragma unroll
    for (int i = 0; i < 6; ++i) wj[i] = cvt(Wa1[i*16 + j]);
    wj[6] = cvt(ba1[j]);
    wj[7] = cvt(Wa2[j]);
  }
  if (tid == 0) {
    ws[OFF_W + 640] = cvt(bg2[0]);
    ws[OFF_W + 641] = cvt(ba2[0]);
    ws[OFF_W + 642] = fmaxf(cvt(apair[0]), 0.f);
    ws[OFF_W + 643] = fmaxf(cvt(ageom[0]), 0.f);
    ws[OFF_W + 644] = fmaxf(cvt(aang[0]), 0.f);
    ws[OFF_W + 645] = fmaxf(cvt(lsc[0]), 0.01f);
  }
}

// ---------------------------------------------------------------------------
// Kernel A: per-batch principal orientation (power iteration) + weight tables
// ---------------------------------------------------------------------------
__global__ __launch_bounds__(256) void prep_kernel(
    const void* __restrict__ xy,
    const void* __restrict__ Wg1, const void* __restrict__ bg1,
    const void* __restrict__ Wg2, const void* __restrict__ bg2,
    const void* __restrict__ Wa1, const void* __restrict__ ba1,
    const void* __restrict__ Wa2, const void* __restrict__ ba2,
    const void* __restrict__ apair, const void* __restrict__ ageom,
    const void* __restrict__ aang, const void* __restrict__ lsc,
    float* __restrict__ ws, VInit vi)
{
  const int b = blockIdx.x, tid = threadIdx.x;
  const int bf = *(volatile const int*)(ws + OFF_FLAG);
  __shared__ float sxy[N_*2];
  __shared__ float red[256][4];

  if (bf) {
    const ushort* p = (const ushort*)xy + b*N_*2;
    for (int i = tid; i < N_*2; i += 256) sxy[i] = cvt(p[i]);
  } else {
    const float* p = (const float*)xy + b*N_*2;
    for (int i = tid; i < N_*2; i += 256) sxy[i] = p[i];
  }
  __syncthreads();

  // pass 1: mean
  float sy = 0.f, sx = 0.f;
  for (int i = tid; i < N_; i += 256) { sy += sxy[2*i]; sx += sxy[2*i+1]; }
  red[tid][0] = sy; red[tid][1] = sx;
  __syncthreads();
  for (int s = 128; s > 0; s >>= 1) {
    if (tid < s) { red[tid][0] += red[tid+s][0]; red[tid][1] += red[tid+s][1]; }
    __syncthreads();
  }
  const float my = red[0][0] / 512.0f;
  const float mx = red[0][1] / 512.0f;
  __syncthreads();

  // pass 2: covariance
  float c00 = 0.f, c01 = 0.f, c11 = 0.f;
  for (int i = tid; i < N_; i += 256) {
    float y = sxy[2*i] - my;
    float x = sxy[2*i+1] - mx;
    c00 += y*y; c01 += y*x; c11 += x*x;
  }
  red[tid][0] = c00; red[tid][1] = c01; red[tid][2] = c11;
  __syncthreads();
  for (int s = 128; s > 0; s >>= 1) {
    if (tid < s) {
      red[tid][0] += red[tid+s][0];
      red[tid][1] += red[tid+s][1];
      red[tid][2] += red[tid+s][2];
    }
    __syncthreads();
  }
  if (tid == 0) {
    float C00 = red[0][0] / 512.0f, C01 = red[0][1] / 512.0f, C11 = red[0][2] / 512.0f;
    float v0 = vi.v[2*b], v1 = vi.v[2*b + 1];
    float nr = sqrtf(v0*v0 + v1*v1) + 1e-8f; v0 /= nr; v1 /= nr;
    for (int it = 0; it < 5; ++it) {
      float w0 = C00*v0 + C01*v1;
      float w1 = C01*v0 + C11*v1;
      nr = sqrtf(w0*w0 + w1*w1) + 1e-8f;
      v0 = w0/nr; v1 = w1/nr;
    }
    float h = sqrtf(v0*v0 + v1*v1);
    ws[OFF_CS + 2*b + 0] = v0 / h;   // cos(theta0)
    ws[OFF_CS + 2*b + 1] = v1 / h;   // sin(theta0)
  }

  if (b == 0) {
    if (bf) build_tables((const ushort*)Wg1, (const ushort*)bg1, (const ushort*)Wg2, (const ushort*)bg2,
                         (const ushort*)Wa1, (const ushort*)ba1, (const ushort*)Wa2, (const ushort*)ba2,
                         (const ushort*)apair, (const ushort*)ageom, (const ushort*)aang, (const ushort*)lsc,
                         ws, tid);
    else    build_tables((const float*)Wg1, (const float*)bg1, (const float*)Wg2, (const float*)bg2,
                         (const float*)Wa1, (const float*)ba1, (const float*)Wa2, (const float*)ba2,
                         (const float*)apair, (const float*)ageom, (const float*)aang, (const float*)lsc,
                         ws, tid);
  }
}

// ---------------------------------------------------------------------------
// Kernel B: fold vertices -> x (f32)
// ---------------------------------------------------------------------------
template <typename T>
__device__ __forceinline__ void fold_body(const T* feats, float* ws, int idx) {
  const int c4 = idx % 96;
  const int bn = idx / 96;
  const int n = bn & (N_ - 1), b = bn >> 9;
  const T* r1 = feats + ((size_t)(b*(2*N_+1) + 1 + 2*n))*C_ + c4*4;
  float4 a = ld4v(r1);
  float4 c = ld4v(r1 + C_);
  float4 o;
  o.x = 0.5f*(a.x + c.x); o.y = 0.5f*(a.y + c.y);
  o.z = 0.5f*(a.z + c.z); o.w = 0.5f*(a.w + c.w);
  *(float4*)(ws + OFF_X + (size_t)idx*4) = o;
}

__global__ __launch_bounds__(256) void fold_kernel(const void* __restrict__ feats,
                                                   float* __restrict__ ws) {
  const int idx = blockIdx.x * 256 + threadIdx.x;
  const int bf = *(volatile const int*)(ws + OFF_FLAG);
  if (bf) fold_body((const ushort*)feats, ws, idx);
  else    fold_body((const float*)feats, ws, idx);
}

// ---------------------------------------------------------------------------
// Kernel C (v2): LDS-tiled register-blocked f32 GEMM for all projections.
//   Grid: (7 col-tiles, 64 row-tiles). Block 256 threads = 64x64 output tile,
//   each thread a 4x4 register tile. Col-tiles 0-2 -> Wq, 3-5 -> Wk,
//   6 -> [Wpi | Wpj | Wd | zero-pad] with bias+relu epilogue.
//   K staged in 32-chunks: lx (x transposed, [c][row]) + lw ([c][col]),
//   stride 68 floats keeps ds_read_b128 16B-aligned and banks spread.
//   Next chunk is register-prefetched before compute (latency hides under
//   the 512 FMAs per chunk).
// ---------------------------------------------------------------------------
#define PKC 32
#define PNKS (C_/PKC)   // 12
#define PLDW 68

template <typename T>
__device__ __forceinline__ float4 load_w_small(const T* Wpi, const T* Wpj,
                                               const T* Wd, int c, int wcq) {
  float v[4];
  #pragma unroll
  for (int k = 0; k < 4; ++k) {
    int col = wcq*4 + k;
    float f = 0.f;
    if (col < 16)      f = cvt(Wpi[c*PH_ + col]);
    else if (col < 32) f = cvt(Wpj[c*PH_ + (col - 16)]);
    else if (col == 32) f = cvt(Wd[c]);
    v[k] = f;
  }
  return make_float4(v[0], v[1], v[2], v[3]);
}

template <typename T>
__device__ void proj2_body(const T* __restrict__ Wq, const T* __restrict__ Wk,
                           const T* __restrict__ Wpi, const T* __restrict__ bpi,
                           const T* __restrict__ Wpj, const T* __restrict__ bpj,
                           const T* __restrict__ Wd,  const T* __restrict__ bd,
                           float* __restrict__ ws)
{
  const int ct  = blockIdx.x;      // 0..6
  const int rt  = blockIdx.y;      // 0..63
  const int tid = threadIdx.x;
  const int row0 = rt * 64;

  __shared__ float lx[PKC][PLDW];
  __shared__ float lw[PKC][PLDW];

  const float* X = ws + OFF_X + (size_t)row0 * C_;

  const bool sm = (ct == 6);
  const T* Wsrc = (ct < 3) ? Wq : Wk;
  const int col0 = (ct < 3) ? ct * 64 : (ct - 3) * 64;

  // staging thread mapping
  const int xrow = tid >> 3, xcq = tid & 7;    // x: 32 rows x 8 float4-chunks; 2 row-halves
  const int wc   = tid >> 4, wcq = tid & 15;   // w: 16 c x 16 float4-chunks; 2 c-halves
  // compute thread mapping
  const int tr = tid >> 4, tc = tid & 15;      // 4x4 tile at rows tr*4, cols tc*4

  float4 px0, px1, pw0, pw1;

  // prologue: prefetch k-chunk 0
  px0 = *(const float4*)(X + (size_t)(xrow     ) * C_ + xcq*4);
  px1 = *(const float4*)(X + (size_t)(xrow + 32) * C_ + xcq*4);
  if (!sm) {
    pw0 = ld4v(Wsrc + (size_t)(wc     ) * HR_ + col0 + wcq*4);
    pw1 = ld4v(Wsrc + (size_t)(wc + 16) * HR_ + col0 + wcq*4);
  } else {
    pw0 = load_w_small(Wpi, Wpj, Wd, wc,      wcq);
    pw1 = load_w_small(Wpi, Wpj, Wd, wc + 16, wcq);
  }

  float acc[4][4] = {{0,0,0,0},{0,0,0,0},{0,0,0,0},{0,0,0,0}};

  for (int ks = 0; ks < PNKS; ++ks) {
    // commit staged registers to LDS
    lx[xcq*4+0][xrow]      = px0.x;
    lx[xcq*4+1][xrow]      = px0.y;
    lx[xcq*4+2][xrow]      = px0.z;
    lx[xcq*4+3][xrow]      = px0.w;
    lx[xcq*4+0][xrow + 32] = px1.x;
    lx[xcq*4+1][xrow + 32] = px1.y;
    lx[xcq*4+2][xrow + 32] = px1.z;
    lx[xcq*4+3][xrow + 32] = px1.w;
    *(float4*)&lw[wc     ][wcq*4] = pw0;
    *(float4*)&lw[wc + 16][wcq*4] = pw1;
    __syncthreads();

    // prefetch next k-chunk into registers (hides under compute below)
    if (ks + 1 < PNKS) {
      const int c0 = (ks + 1) * PKC;
      px0 = *(const float4*)(X + (size_t)(xrow     ) * C_ + c0 + xcq*4);
      px1 = *(const float4*)(X + (size_t)(xrow + 32) * C_ + c0 + xcq*4);
      if (!sm) {
        pw0 = ld4v(Wsrc + (size_t)(c0 + wc     ) * HR_ + col0 + wcq*4);
        pw1 = ld4v(Wsrc + (size_t)(c0 + wc + 16) * HR_ + col0 + wcq*4);
      } else {
        pw0 = load_w_small(Wpi, Wpj, Wd, c0 + wc,      wcq);
        pw1 = load_w_small(Wpi, Wpj, Wd, c0 + wc + 16, wcq);
      }
    }

    // 4x4 register-tile FMA over the staged chunk
    #pragma unroll
    for (int c = 0; c < PKC; ++c) {
      float4 xv = *(const float4*)&lx[c][tr*4];   // 4 rows (broadcast across tc)
      float4 wv = *(const float4*)&lw[c][tc*4];   // 4 cols (2-way bank, free)
      acc[0][0] = fmaf(xv.x, wv.x, acc[0][0]);
      acc[0][1] = fmaf(xv.x, wv.y, acc[0][1]);
      acc[0][2] = fmaf(xv.x, wv.z, acc[0][2]);
      acc[0][3] = fmaf(xv.x, wv.w, acc[0][3]);
      acc[1][0] = fmaf(xv.y, wv.x, acc[1][0]);
      acc[1][1] = fmaf(xv.y, wv.y, acc[1][1]);
      acc[1][2] = fmaf(xv.y, wv.z, acc[1][2]);
      acc[1][3] = fmaf(xv.y, wv.w, acc[1][3]);
      acc[2][0] = fmaf(xv.z, wv.x, acc[2][0]);
      acc[2][1] = fmaf(xv.z, wv.y, acc[2][1]);
      acc[2][2] = fmaf(xv.z, wv.z, acc[2][2]);
      acc[2][3] = fmaf(xv.z, wv.w, acc[2][3]);
      acc[3][0] = fmaf(xv.w, wv.x, acc[3][0]);
      acc[3][1] = fmaf(xv.w, wv.y, acc[3][1]);
      acc[3][2] = fmaf(xv.w, wv.z, acc[3][2]);
      acc[3][3] = fmaf(xv.w, wv.w, acc[3][3]);
    }
    __syncthreads();
  }

  // epilogue
  if (!sm) {
    float* base = ws + ((ct < 3) ? OFF_Q : OFF_K);
    #pragma unroll
    for (int r = 0; r < 4; ++r) {
      const int row = row0 + tr*4 + r;
      *(float4*)(base + (size_t)row * HR_ + col0 + tc*4) =
          make_float4(acc[r][0], acc[r][1], acc[r][2], acc[r][3]);
    }
  } else {
    #pragma unroll
    for (int r = 0; r < 4; ++r) {
      const int row = row0 + tr*4 + r;
      #pragma unroll
      for (int k = 0; k < 4; ++k) {
        const int col = tc*4 + k;
        if (col < 16) {
          ws[OFF_A + (size_t)row * PH_ + col] =
              fmaxf(acc[r][k] + cvt(bpi[col]), 0.f);
        } else if (col < 32) {
          ws[OFF_BJ + (size_t)row * PH_ + (col - 16)] =
              fmaxf(acc[r][k] + cvt(bpj[col - 16]), 0.f);
        } else if (col == 32) {
          ws[OFF_D + row] = acc[r][k] + cvt(bd[0]);
        }
      }
    }
  }
}

__global__ __launch_bounds__(256) void proj_kernel(
    const void* __restrict__ Wq, const void* __restrict__ Wk,
    const void* __restrict__ Wpi, const void* __restrict__ bpi,
    const void* __restrict__ Wpj, const void* __restrict__ bpj,
    const void* __restrict__ Wd,  const void* __restrict__ bd,
    float* __restrict__ ws)
{
  const int bf = *(volatile const int*)(ws + OFF_FLAG);
  if (bf) proj2_body((const ushort*)Wq, (const ushort*)Wk, (const ushort*)Wpi, (const ushort*)bpi,
                     (const ushort*)Wpj, (const ushort*)bpj, (const ushort*)Wd, (const ushort*)bd, ws);
  else    proj2_body((const float*)Wq, (const float*)Wk, (const float*)Wpi, (const float*)bpi,
                     (const float*)Wpj, (const float*)bpj, (const float*)Wd, (const float*)bd, ws);
}

// ---------------------------------------------------------------------------
// Kernel D: fused score assembly
// ---------------------------------------------------------------------------
__global__ __launch_bounds__(256, 2) void score_kernel(
    const void* __restrict__ xy, const float* __restrict__ ws,
    void* __restrict__ out)
{
  const int b  = blockIdx.z;
  const int n0 = blockIdx.y * 32, m0 = blockIdx.x * 32;
  const int tid = threadIdx.x;
  const int bf = *(volatile const int*)(ws + OFF_FLAG);

  __shared__ float Qt[32][196];   // pad 192->196: rows land on distinct banks
  __shared__ float Kt[32][196];
  __shared__ float At[32][20];    // pad 16->20
  __shared__ float Bt[32][20];
  __shared__ float xyn[32][2], xym[32][2], dn[32];

  const float* Qg = ws + OFF_Q + ((size_t)(b*N_) + n0) * HR_;
  const float* Kg = ws + OFF_K + ((size_t)(b*N_) + m0) * HR_;
  for (int i = tid; i < 1536; i += 256) {
    int row = i / 48, c = (i % 48) * 4;
    *(float4*)&Qt[row][c] = *(const float4*)(Qg + row*HR_ + c);
    *(float4*)&Kt[row][c] = *(const float4*)(Kg + row*HR_ + c);
  }
  const float* Ag = ws + OFF_A  + ((size_t)(b*N_) + n0) * PH_;
  const float* Bg = ws + OFF_BJ + ((size_t)(b*N_) + m0) * PH_;
  for (int i = tid; i < 128; i += 256) {
    int row = i / 4, c = (i % 4) * 4;
    *(float4*)&At[row][c] = *(const float4*)(Ag + row*PH_ + c);
    *(float4*)&Bt[row][c] = *(const float4*)(Bg + row*PH_ + c);
  }
  if (bf) {
    const ushort* p = (const ushort*)xy;
    if (tid < 32) {
      xyn[tid][0] = cvt(p[((b*N_) + n0 + tid)*2 + 0]);
      xyn[tid][1] = cvt(p[((b*N_) + n0 + tid)*2 + 1]);
      xym[tid][0] = cvt(p[((b*N_) + m0 + tid)*2 + 0]);
      xym[tid][1] = cvt(p[((b*N_) + m0 + tid)*2 + 1]);
      dn[tid] = ws[OFF_D + b*N_ + n0 + tid];
    }
  } else {
    const float* p = (const float*)xy;
    if (tid < 32) {
      xyn[tid][0] = p[((b*N_) + n0 + tid)*2 + 0];
      xyn[tid][1] = p[((b*N_) + n0 + tid)*2 + 1];
      xym[tid][0] = p[((b*N_) + m0 + tid)*2 + 0];
      xym[tid][1] = p[((b*N_) + m0 + tid)*2 + 1];
      dn[tid] = ws[OFF_D + b*N_ + n0 + tid];
    }
  }
  __syncthreads();

  const float c0 = ws[OFF_CS + 2*b], s0 = ws[OFF_CS + 2*b + 1];
  const float* wsm = ws + OFF_W;
  const float bg2v = wsm[640], ba2v = wsm[641];
  const float ap = wsm[642], ag = wsm[643], aa = wsm[644], ls = wsm[645];

  const int nl = tid >> 3, mg = tid & 7;   // thread: row nl, 4 cols mg+8p

  float accQ[4] = {0,0,0,0}, accP[4] = {0,0,0,0};
  #pragma unroll 4
  for (int c = 0; c < HR_; c += 4) {
    float4 q = *(const float4*)&Qt[nl][c];
    #pragma unroll
    for (int p = 0; p < 4; ++p) {
      float4 k = *(const float4*)&Kt[mg + 8*p][c];
      accQ[p] = fmaf(q.x,k.x, fmaf(q.y,k.y, fmaf(q.z,k.z, fmaf(q.w,k.w, accQ[p]))));
    }
  }
  #pragma unroll
  for (int c = 0; c < PH_; c += 4) {
    float4 a = *(const float4*)&At[nl][c];
    #pragma unroll
    for (int p = 0; p < 4; ++p) {
      float4 v = *(const float4*)&Bt[mg + 8*p][c];
      accP[p] = fmaf(a.x,v.x, fmaf(a.y,v.y, fmaf(a.z,v.z, fmaf(a.w,v.w, accP[p]))));
    }
  }

  // geometry features (rotation identities; no atan2/sin/cos needed)
  const float STEP  = 1.41421354f / 7.0f;
  const float GAMMA = 1.0f / (2.0f*STEP*STEP + 1e-8f);
  const float yn = xyn[nl][0], xn = xyn[nl][1];
  float DY[4], DX[4], C1[4], S1[4], C2[4], S2[4], C4v[4], S4[4], PHI[4][8];
  #pragma unroll
  for (int p = 0; p < 4; ++p) {
    int ml = mg + 8*p;
    float dy = yn - xym[ml][0], dx = xn - xym[ml][1];
    DY[p] = dy; DX[p] = dx;
    float h2 = fmaf(dx, dx, dy*dy);
    float r = sqrtf(h2 + 1e-8f);
    float ct, st;
    if (h2 > 0.f) { float ih = 1.0f / sqrtf(h2); ct = dx*ih; st = dy*ih; }
    else          { ct = 1.f; st = 0.f; }             // atan2(0,0)=0
    float c1 = ct*c0 + st*s0;                         // cos(theta - theta0)
    float s1 = st*c0 - ct*s0;                         // sin(theta - theta0)
    C1[p] = c1; S1[p] = s1;
    float c2 = c1*c1 - s1*s1, s2 = 2.f*c1*s1;
    C2[p] = c2; S2[p] = s2;
    C4v[p] = c2*c2 - s2*s2; S4[p] = 2.f*c2*s2;
    #pragma unroll
    for (int k = 0; k < 8; ++k) {
      float d = r - (float)k * STEP;
      PHI[p][k] = __expf(-GAMMA * d * d);
    }
  }

  // G MLP: 12 -> 32 -> 1 (weights via uniform scalar loads)
  float g[4] = {0,0,0,0};
  #pragma unroll 4
  for (int j = 0; j < 32; ++j) {
    const float* wj = wsm + j*16;
    #pragma unroll
    for (int p = 0; p < 4; ++p) {
      float h = fmaf(DY[p], wj[0], fmaf(DX[p], wj[1], wj[12]));
      #pragma unroll
      for (int k = 0; k < 8; ++k) h = fmaf(PHI[p][k], wj[2+k], h);
      h = fmaf(C1[p], wj[10], fmaf(S1[p], wj[11], h));
      g[p] = fmaf(fmaxf(h, 0.f), wj[13], g[p]);
    }
  }

  // angle MLP: 6 -> 16 -> 1
  float hb[4] = {0,0,0,0};
  #pragma unroll 4
  for (int j = 0; j < 16; ++j) {
    const float* wj = wsm + 512 + j*8;
    #pragma unroll
    for (int p = 0; p < 4; ++p) {
      float h = fmaf(C1[p],  wj[0], fmaf(S1[p], wj[1], wj[6]));
      h = fmaf(C2[p],  wj[2], fmaf(S2[p], wj[3], h));
      h = fmaf(C4v[p], wj[4], fmaf(S4[p], wj[5], h));
      hb[p] = fmaf(fmaxf(h, 0.f), wj[7], hb[p]);
    }
  }

  const int n_g = n0 + nl;
  #pragma unroll
  for (int p = 0; p < 4; ++p) {
    const int m_g = m0 + mg + 8*p;
    float S = HEAD_SCALE_*accQ[p] + ap*accP[p] + ag*(g[p] + bg2v) + aa*(hb[p] + ba2v);
    if (n_g == m_g) S += dn[nl];
    S *= ls;
    const size_t oi = ((size_t)(b*N_) + n_g)*N_ + m_g;
    if (bf) ((__hip_bfloat16*)out)[oi] = __float2bfloat16(S);
    else    ((float*)out)[oi] = S;
  }
}

// ---------------------------------------------------------------------------
// Host: replicate jax.random.normal(key(42), (8,2,1)) — threefry2x32
// (partitionable mode) + XLA/Giles f32 erfinv.
// ---------------------------------------------------------------------------
static inline uint32_t rotl32(uint32_t x, int d) { return (x << d) | (x >> (32 - d)); }

static void threefry2x32_host(uint32_t k0, uint32_t k1, uint32_t& x0, uint32_t& x1) {
  const uint32_t ks0 = k0, ks1 = k1, ks2 = k0 ^ k1 ^ 0x1BD11BDAu;
  static const int R[2][4] = {{13,15,26,6},{17,29,16,24}};
  x0 += ks0; x1 += ks1;
  const uint32_t ks[3] = {ks0, ks1, ks2};
  for (int i = 0; i < 5; ++i) {
    const int* r = R[i & 1];
    for (int j = 0; j < 4; ++j) { x0 += x1; x1 = rotl32(x1, r[j]); x1 ^= x0; }
    x0 += ks[(i + 1) % 3];
    x1 += ks[(i + 2) % 3] + (uint32_t)(i + 1);
  }
}

static float erfinv_host(float x) {
  float w = -log1pf(-x * x);
  float p;
  if (w < 5.0f) {
    w = w - 2.5f;
    p = 2.81022636e-08f;
    p = fmaf(p, w, 3.43273939e-07f);
    p = fmaf(p, w, -3.5233877e-06f);
    p = fmaf(p, w, -4.39150654e-06f);
    p = fmaf(p, w, 0.00021858087f);
    p = fmaf(p, w, -0.00125372503f);
    p = fmaf(p, w, -0.00417768164f);
    p = fmaf(p, w, 0.246640727f);
    p = fmaf(p, w, 1.50140941f);
  } else {
    w = sqrtf(w) - 3.0f;
    p = -0.000200214257f;
    p = fmaf(p, w, 0.000100950558f);
    p = fmaf(p, w, 0.00134934322f);
    p = fmaf(p, w, -0.00367342844f);
    p = fmaf(p, w, 0.00573950773f);
    p = fmaf(p, w, -0.0076224613f);
    p = fmaf(p, w, 0.00943887047f);
    p = fmaf(p, w, 1.00167406f);
    p = fmaf(p, w, 2.83297682f);
  }
  return p * x;
}

static VInit make_vinit() {
  VInit vi;
  for (int i = 0; i < 16; ++i) {
    uint32_t o0 = 0u, o1 = (uint32_t)i;
    threefry2x32_host(0u, 42u, o0, o1);
    uint32_t bits = o0 ^ o1;
    uint32_t fb = (bits >> 9) | 0x3f800000u;
    float f; memcpy(&f, &fb, 4); f -= 1.0f;
    const float lo = -0.99999994f;
    float u = f * 2.0f + lo;
    if (u < lo) u = lo;
    vi.v[i] = 1.41421354f * erfinv_host(u);
  }
  return vi;
}

// ---------------------------------------------------------------------------
extern "C" void kernel_launch(void* const* d_in, const int* in_sizes, int n_in,
                              void* d_out, int out_size, void* d_ws, size_t ws_size,
                              hipStream_t stream) {
  (void)in_sizes; (void)n_in; (void)out_size;
  if (ws_size < (size_t)WS_FLOATS * sizeof(float)) return;

  const void* feats = d_in[0];
  const void* xy    = d_in[1];
  const void* Wq    = d_in[2];
  const void* Wk    = d_in[3];
  const void* Wpi   = d_in[4];
  const void* bpi   = d_in[5];
  const void* Wpj   = d_in[6];
  const void* bpj   = d_in[7];
  const void* apair = d_in[8];
  const void* Wg1   = d_in[9];
  const void* bg1   = d_in[10];
  const void* bg2w  = d_in[11];  // Wg2
  const void* bg2b  = d_in[12];  // bg2
  const void* ageom = d_in[13];
  const void* Wa1   = d_in[14];
  const void* ba1   = d_in[15];
  const void* Wa2   = d_in[16];
  const void* ba2   = d_in[17];
  const void* aang  = d_in[18];
  const void* Wd    = d_in[19];
  const void* bd    = d_in[20];
  const void* lsc   = d_in[21];
  float* ws = (float*)d_ws;

  VInit vi = make_vinit();

  hipLaunchKernelGGL(detect_kernel, dim3(1), dim3(64), 0, stream,
      (const uint32_t*)Wg1, ws);
  hipLaunchKernelGGL(prep_kernel, dim3(B_), dim3(256), 0, stream,
      xy, Wg1, bg1, bg2w, bg2b, Wa1, ba1, Wa2, ba2, apair, ageom, aang, lsc, ws, vi);
  hipLaunchKernelGGL(fold_kernel, dim3(1536), dim3(256), 0, stream, feats, ws);
  hipLaunchKernelGGL(proj_kernel, dim3(7, 64), dim3(256), 0, stream,
      Wq, Wk, Wpi, bpi, Wpj, bpj, Wd, bd, ws);
  hipLaunchKernelGGL(score_kernel, dim3(16, 16, B_), dim3(256), 0, stream,
      xy, ws, d_out);
}

// Round 2
// 222.009 us; speedup vs baseline: 1.4031x; 1.0078x over previous
//
#include <hip/hip_runtime.h>
#include <hip/hip_bf16.h>
#include <stdint.h>
#include <string.h>
#include <math.h>

// Problem constants
#define B_ 8
#define N_ 512
#define C_ 384
#define HR_ 192          // H*R = 6*32
#define PH_ 16           // PAIR_HIDDEN
#define HEAD_SCALE_ 0.17677669529663687f
#define QK2W_ 224        // bf16 packed row: 192 Q/K | 16 pair | 16 zero

// Workspace layout (float offsets)
#define OFF_X   0
#define OFF_Q   (B_*N_*C_)
#define OFF_K   (OFF_Q + B_*N_*HR_)
#define OFF_A   (OFF_K + B_*N_*HR_)
#define OFF_BJ  (OFF_A + B_*N_*PH_)
#define OFF_D   (OFF_BJ + B_*N_*PH_)
#define OFF_CS  (OFF_D + B_*N_)
#define OFF_W   (OFF_CS + 2*B_)
#define OFF_FLAG (OFF_W + 700)               // int: 1 = inputs are bf16, 0 = f32
#define WS_FLOATS (OFF_W + 768)

struct VInit { float v[16]; };

typedef __attribute__((ext_vector_type(8))) short short8v;
typedef __attribute__((ext_vector_type(4))) float f32x4;

__device__ __forceinline__ float cvt(ushort u) {
  union { uint32_t i; float f; } x; x.i = ((uint32_t)u) << 16; return x.f;
}
__device__ __forceinline__ float cvt(float f) { return f; }

__device__ __forceinline__ ushort f2bf(float f) {
  __hip_bfloat16 h = __float2bfloat16(f);
  union { __hip_bfloat16 b; ushort u; } x; x.b = h; return x.u;
}

__device__ __forceinline__ float4 ld4v(const ushort* p) {
  ushort4 u = *(const ushort4*)p;
  return make_float4(cvt(u.x), cvt(u.y), cvt(u.z), cvt(u.w));
}
__device__ __forceinline__ float4 ld4v(const float* p) { return *(const float4*)p; }

// ---------------------------------------------------------------------------
// Kernel 0: dtype detection. If Wg1 holds bf16, the low ushort of each dword
// decodes to a sane-magnitude bf16 (N(0,0.3) weights). If it holds f32, the
// low 16 bits are uniform mantissa bits (sane-decode prob ~10%). 128 dwords
// are valid to read under both layouts (512 B <= min(768, 1536) B).
// ---------------------------------------------------------------------------
__global__ void detect_kernel(const uint32_t* __restrict__ wg1, float* __restrict__ ws) {
  if (threadIdx.x == 0 && blockIdx.x == 0) {
    int cnt = 0;
    for (int i = 0; i < 128; ++i) {
      uint32_t d = wg1[i];
      float v = cvt((ushort)(d & 0xFFFFu));
      float av = fabsf(v);
      if (av == 0.0f || (av >= 9.5367431640625e-07f && av <= 32.0f)) ++cnt;
    }
    *(int*)(ws + OFF_FLAG) = (cnt >= 64) ? 1 : 0;
  }
}

// ---------------------------------------------------------------------------
// Weight tables (transposed for uniform scalar loads in score kernel)
// ---------------------------------------------------------------------------
template <typename T>
__device__ void build_tables(const T* Wg1, const T* bg1, const T* Wg2, const T* bg2,
                             const T* Wa1, const T* ba1, const T* Wa2, const T* ba2,
                             const T* apair, const T* ageom, const T* aang, const T* lsc,
                             float* ws, int tid) {
  for (int j = tid; j < 32; j += 256) {
    float* wj = ws + OFF_W + j*16;
    #pragma unroll
    for (int i = 0; i < 12; ++i) wj[i] = cvt(Wg1[i*32 + j]);
    wj[12] = cvt(bg1[j]);
    wj[13] = cvt(Wg2[j]);
    wj[14] = 0.f; wj[15] = 0.f;
  }
  for (int j = tid; j < 16; j += 256) {
    float* wj = ws + OFF_W + 512 + j*8;
    #pragma unroll
    for (int i = 0; i < 6; ++i) wj[i] = cvt(Wa1[i*16 + j]);
    wj[6] = cvt(ba1[j]);
    wj[7] = cvt(Wa2[j]);
  }
  if (tid == 0) {
    ws[OFF_W + 640] = cvt(bg2[0]);
    ws[OFF_W + 641] = cvt(ba2[0]);
    ws[OFF_W + 642] = fmaxf(cvt(apair[0]), 0.f);
    ws[OFF_W + 643] = fmaxf(cvt(ageom[0]), 0.f);
    ws[OFF_W + 644] = fmaxf(cvt(aang[0]), 0.f);
    ws[OFF_W + 645] = fmaxf(cvt(lsc[0]), 0.01f);
  }
}

// ---------------------------------------------------------------------------
// Kernel A: per-batch principal orientation (power iteration) + weight tables
// ---------------------------------------------------------------------------
__global__ __launch_bounds__(256) void prep_kernel(
    const void* __restrict__ xy,
    const void* __restrict__ Wg1, const void* __restrict__ bg1,
    const void* __restrict__ Wg2, const void* __restrict__ bg2,
    const void* __restrict__ Wa1, const void* __restrict__ ba1,
    const void* __restrict__ Wa2, const void* __restrict__ ba2,
    const void* __restrict__ apair, const void* __restrict__ ageom,
    const void* __restrict__ aang, const void* __restrict__ lsc,
    float* __restrict__ ws, VInit vi)
{
  const int b = blockIdx.x, tid = threadIdx.x;
  const int bf = *(volatile const int*)(ws + OFF_FLAG);
  __shared__ float sxy[N_*2];
  __shared__ float red[256][4];

  if (bf) {
    const ushort* p = (const ushort*)xy + b*N_*2;
    for (int i = tid; i < N_*2; i += 256) sxy[i] = cvt(p[i]);
  } else {
    const float* p = (const float*)xy + b*N_*2;
    for (int i = tid; i < N_*2; i += 256) sxy[i] = p[i];
  }
  __syncthreads();

  // pass 1: mean
  float sy = 0.f, sx = 0.f;
  for (int i = tid; i < N_; i += 256) { sy += sxy[2*i]; sx += sxy[2*i+1]; }
  red[tid][0] = sy; red[tid][1] = sx;
  __syncthreads();
  for (int s = 128; s > 0; s >>= 1) {
    if (tid < s) { red[tid][0] += red[tid+s][0]; red[tid][1] += red[tid+s][1]; }
    __syncthreads();
  }
  const float my = red[0][0] / 512.0f;
  const float mx = red[0][1] / 512.0f;
  __syncthreads();

  // pass 2: covariance
  float c00 = 0.f, c01 = 0.f, c11 = 0.f;
  for (int i = tid; i < N_; i += 256) {
    float y = sxy[2*i] - my;
    float x = sxy[2*i+1] - mx;
    c00 += y*y; c01 += y*x; c11 += x*x;
  }
  red[tid][0] = c00; red[tid][1] = c01; red[tid][2] = c11;
  __syncthreads();
  for (int s = 128; s > 0; s >>= 1) {
    if (tid < s) {
      red[tid][0] += red[tid+s][0];
      red[tid][1] += red[tid+s][1];
      red[tid][2] += red[tid+s][2];
    }
    __syncthreads();
  }
  if (tid == 0) {
    float C00 = red[0][0] / 512.0f, C01 = red[0][1] / 512.0f, C11 = red[0][2] / 512.0f;
    float v0 = vi.v[2*b], v1 = vi.v[2*b + 1];
    float nr = sqrtf(v0*v0 + v1*v1) + 1e-8f; v0 /= nr; v1 /= nr;
    for (int it = 0; it < 5; ++it) {
      float w0 = C00*v0 + C01*v1;
      float w1 = C01*v0 + C11*v1;
      nr = sqrtf(w0*w0 + w1*w1) + 1e-8f;
      v0 = w0/nr; v1 = w1/nr;
    }
    float h = sqrtf(v0*v0 + v1*v1);
    ws[OFF_CS + 2*b + 0] = v0 / h;   // cos(theta0)
    ws[OFF_CS + 2*b + 1] = v1 / h;   // sin(theta0)
  }

  if (b == 0) {
    if (bf) build_tables((const ushort*)Wg1, (const ushort*)bg1, (const ushort*)Wg2, (const ushort*)bg2,
                         (const ushort*)Wa1, (const ushort*)ba1, (const ushort*)Wa2, (const ushort*)ba2,
                         (const ushort*)apair, (const ushort*)ageom, (const ushort*)aang, (const ushort*)lsc,
                         ws, tid);
    else    build_tables((const float*)Wg1, (const float*)bg1, (const float*)Wg2, (const float*)bg2,
                         (const float*)Wa1, (const float*)ba1, (const float*)Wa2, (const float*)ba2,
                         (const float*)apair, (const float*)ageom, (const float*)aang, (const float*)lsc,
                         ws, tid);
  }
}

// ---------------------------------------------------------------------------
// Kernel B: fold vertices -> x (f32)
// ---------------------------------------------------------------------------
template <typename T>
__device__ __forceinline__ void fold_body(const T* feats, float* ws, int idx) {
  const int c4 = idx % 96;
  const int bn = idx / 96;
  const int n = bn & (N_ - 1), b = bn >> 9;
  const T* r1 = feats + ((size_t)(b*(2*N_+1) + 1 + 2*n))*C_ + c4*4;
  float4 a = ld4v(r1);
  float4 c = ld4v(r1 + C_);
  float4 o;
  o.x = 0.5f*(a.x + c.x); o.y = 0.5f*(a.y + c.y);
  o.z = 0.5f*(a.z + c.z); o.w = 0.5f*(a.w + c.w);
  *(float4*)(ws + OFF_X + (size_t)idx*4) = o;
}

__global__ __launch_bounds__(256) void fold_kernel(const void* __restrict__ feats,
                                                   float* __restrict__ ws) {
  const int idx = blockIdx.x * 256 + threadIdx.x;
  const int bf = *(volatile const int*)(ws + OFF_FLAG);
  if (bf) fold_body((const ushort*)feats, ws, idx);
  else    fold_body((const float*)feats, ws, idx);
}

// ---------------------------------------------------------------------------
// Kernel C (v2): LDS-tiled register-blocked f32 GEMM for all projections.
//   Grid: (7 col-tiles, 64 row-tiles). Block 256 threads = 64x64 output tile,
//   each thread a 4x4 register tile. Col-tiles 0-2 -> Wq, 3-5 -> Wk,
//   6 -> [Wpi | Wpj | Wd | zero-pad] with bias+relu epilogue.
//   bf16 mode epilogue packs Q/K rows (width 224 bf16):
//     Q2 = [HEAD_SCALE*Q | alpha_pair*relu(x@Wpi+bpi) | 0]
//     K2 = [K            | relu(x@Wpj+bpj)            | 0]
//   so score's MFMA computes HEAD_SCALE*QK^T + alpha_pair*a_i.b_j in one go.
// ---------------------------------------------------------------------------
#define PKC 32
#define PNKS (C_/PKC)   // 12
#define PLDW 68

template <typename T>
__device__ __forceinline__ float4 load_w_small(const T* Wpi, const T* Wpj,
                                               const T* Wd, int c, int wcq) {
  float v[4];
  #pragma unroll
  for (int k = 0; k < 4; ++k) {
    int col = wcq*4 + k;
    float f = 0.f;
    if (col < 16)      f = cvt(Wpi[c*PH_ + col]);
    else if (col < 32) f = cvt(Wpj[c*PH_ + (col - 16)]);
    else if (col == 32) f = cvt(Wd[c]);
    v[k] = f;
  }
  return make_float4(v[0], v[1], v[2], v[3]);
}

template <typename T>
__device__ void proj2_body(const T* __restrict__ Wq, const T* __restrict__ Wk,
                           const T* __restrict__ Wpi, const T* __restrict__ bpi,
                           const T* __restrict__ Wpj, const T* __restrict__ bpj,
                           const T* __restrict__ Wd,  const T* __restrict__ bd,
                           float* __restrict__ ws)
{
  const int ct  = blockIdx.x;      // 0..6
  const int rt  = blockIdx.y;      // 0..63
  const int tid = threadIdx.x;
  const int row0 = rt * 64;

  __shared__ float lx[PKC][PLDW];
  __shared__ float lw[PKC][PLDW];

  const float* X = ws + OFF_X + (size_t)row0 * C_;

  const bool sm = (ct == 6);
  const T* Wsrc = (ct < 3) ? Wq : Wk;
  const int col0 = (ct < 3) ? ct * 64 : (ct - 3) * 64;

  // staging thread mapping
  const int xrow = tid >> 3, xcq = tid & 7;    // x: 32 rows x 8 float4-chunks; 2 row-halves
  const int wc   = tid >> 4, wcq = tid & 15;   // w: 16 c x 16 float4-chunks; 2 c-halves
  // compute thread mapping
  const int tr = tid >> 4, tc = tid & 15;      // 4x4 tile at rows tr*4, cols tc*4

  float4 px0, px1, pw0, pw1;

  // prologue: prefetch k-chunk 0
  px0 = *(const float4*)(X + (size_t)(xrow     ) * C_ + xcq*4);
  px1 = *(const float4*)(X + (size_t)(xrow + 32) * C_ + xcq*4);
  if (!sm) {
    pw0 = ld4v(Wsrc + (size_t)(wc     ) * HR_ + col0 + wcq*4);
    pw1 = ld4v(Wsrc + (size_t)(wc + 16) * HR_ + col0 + wcq*4);
  } else {
    pw0 = load_w_small(Wpi, Wpj, Wd, wc,      wcq);
    pw1 = load_w_small(Wpi, Wpj, Wd, wc + 16, wcq);
  }

  float acc[4][4] = {{0,0,0,0},{0,0,0,0},{0,0,0,0},{0,0,0,0}};

  for (int ks = 0; ks < PNKS; ++ks) {
    // commit staged registers to LDS
    lx[xcq*4+0][xrow]      = px0.x;
    lx[xcq*4+1][xrow]      = px0.y;
    lx[xcq*4+2][xrow]      = px0.z;
    lx[xcq*4+3][xrow]      = px0.w;
    lx[xcq*4+0][xrow + 32] = px1.x;
    lx[xcq*4+1][xrow + 32] = px1.y;
    lx[xcq*4+2][xrow + 32] = px1.z;
    lx[xcq*4+3][xrow + 32] = px1.w;
    *(float4*)&lw[wc     ][wcq*4] = pw0;
    *(float4*)&lw[wc + 16][wcq*4] = pw1;
    __syncthreads();

    // prefetch next k-chunk into registers (hides under compute below)
    if (ks + 1 < PNKS) {
      const int c0 = (ks + 1) * PKC;
      px0 = *(const float4*)(X + (size_t)(xrow     ) * C_ + c0 + xcq*4);
      px1 = *(const float4*)(X + (size_t)(xrow + 32) * C_ + c0 + xcq*4);
      if (!sm) {
        pw0 = ld4v(Wsrc + (size_t)(c0 + wc     ) * HR_ + col0 + wcq*4);
        pw1 = ld4v(Wsrc + (size_t)(c0 + wc + 16) * HR_ + col0 + wcq*4);
      } else {
        pw0 = load_w_small(Wpi, Wpj, Wd, c0 + wc,      wcq);
        pw1 = load_w_small(Wpi, Wpj, Wd, c0 + wc + 16, wcq);
      }
    }

    // 4x4 register-tile FMA over the staged chunk
    #pragma unroll
    for (int c = 0; c < PKC; ++c) {
      float4 xv = *(const float4*)&lx[c][tr*4];   // 4 rows (broadcast across tc)
      float4 wv = *(const float4*)&lw[c][tc*4];   // 4 cols (2-way bank, free)
      acc[0][0] = fmaf(xv.x, wv.x, acc[0][0]);
      acc[0][1] = fmaf(xv.x, wv.y, acc[0][1]);
      acc[0][2] = fmaf(xv.x, wv.z, acc[0][2]);
      acc[0][3] = fmaf(xv.x, wv.w, acc[0][3]);
      acc[1][0] = fmaf(xv.y, wv.x, acc[1][0]);
      acc[1][1] = fmaf(xv.y, wv.y, acc[1][1]);
      acc[1][2] = fmaf(xv.y, wv.z, acc[1][2]);
      acc[1][3] = fmaf(xv.y, wv.w, acc[1][3]);
      acc[2][0] = fmaf(xv.z, wv.x, acc[2][0]);
      acc[2][1] = fmaf(xv.z, wv.y, acc[2][1]);
      acc[2][2] = fmaf(xv.z, wv.z, acc[2][2]);
      acc[2][3] = fmaf(xv.z, wv.w, acc[2][3]);
      acc[3][0] = fmaf(xv.w, wv.x, acc[3][0]);
      acc[3][1] = fmaf(xv.w, wv.y, acc[3][1]);
      acc[3][2] = fmaf(xv.w, wv.z, acc[3][2]);
      acc[3][3] = fmaf(xv.w, wv.w, acc[3][3]);
    }
    __syncthreads();
  }

  // epilogue
  if constexpr (sizeof(T) == 2) {
    // bf16 mode: pack into Q2/K2 (224-wide bf16 rows) for the MFMA score path
    ushort* q2 = (ushort*)(ws + OFF_Q);
    ushort* k2 = (ushort*)(ws + OFF_K);
    if (!sm) {
      ushort* base = (ct < 3) ? q2 : k2;
      const float sc = (ct < 3) ? HEAD_SCALE_ : 1.0f;
      #pragma unroll
      for (int r = 0; r < 4; ++r) {
        const int row = row0 + tr*4 + r;
        ushort4 o = make_ushort4(f2bf(sc*acc[r][0]), f2bf(sc*acc[r][1]),
                                 f2bf(sc*acc[r][2]), f2bf(sc*acc[r][3]));
        *(ushort4*)(base + (size_t)row*QK2W_ + col0 + tc*4) = o;
      }
    } else {
      // zero the k=208..223 pad slots for the 64 rows of this tile
      {
        const int row = row0 + (tid >> 2), ch = tid & 3;
        ushort4 z = make_ushort4(0,0,0,0);
        *(ushort4*)(q2 + (size_t)row*QK2W_ + 208 + ch*4) = z;
        *(ushort4*)(k2 + (size_t)row*QK2W_ + 208 + ch*4) = z;
      }
      const float ap = ws[OFF_W + 642];
      #pragma unroll
      for (int r = 0; r < 4; ++r) {
        const int row = row0 + tr*4 + r;
        #pragma unroll
        for (int k = 0; k < 4; ++k) {
          const int col = tc*4 + k;
          if (col < 16) {
            q2[(size_t)row*QK2W_ + 192 + col] =
                f2bf(ap * fmaxf(acc[r][k] + cvt(bpi[col]), 0.f));
          } else if (col < 32) {
            k2[(size_t)row*QK2W_ + 192 + (col - 16)] =
                f2bf(fmaxf(acc[r][k] + cvt(bpj[col - 16]), 0.f));
          } else if (col == 32) {
            ws[OFF_D + row] = acc[r][k] + cvt(bd[0]);
          }
        }
      }
    }
  } else {
    // f32 mode: original layout
    if (!sm) {
      float* base = ws + ((ct < 3) ? OFF_Q : OFF_K);
      #pragma unroll
      for (int r = 0; r < 4; ++r) {
        const int row = row0 + tr*4 + r;
        *(float4*)(base + (size_t)row * HR_ + col0 + tc*4) =
            make_float4(acc[r][0], acc[r][1], acc[r][2], acc[r][3]);
      }
    } else {
      #pragma unroll
      for (int r = 0; r < 4; ++r) {
        const int row = row0 + tr*4 + r;
        #pragma unroll
        for (int k = 0; k < 4; ++k) {
          const int col = tc*4 + k;
          if (col < 16) {
            ws[OFF_A + (size_t)row * PH_ + col] =
                fmaxf(acc[r][k] + cvt(bpi[col]), 0.f);
          } else if (col < 32) {
            ws[OFF_BJ + (size_t)row * PH_ + (col - 16)] =
                fmaxf(acc[r][k] + cvt(bpj[col - 16]), 0.f);
          } else if (col == 32) {
            ws[OFF_D + row] = acc[r][k] + cvt(bd[0]);
          }
        }
      }
    }
  }
}

__global__ __launch_bounds__(256) void proj_kernel(
    const void* __restrict__ Wq, const void* __restrict__ Wk,
    const void* __restrict__ Wpi, const void* __restrict__ bpi,
    const void* __restrict__ Wpj, const void* __restrict__ bpj,
    const void* __restrict__ Wd,  const void* __restrict__ bd,
    float* __restrict__ ws)
{
  const int bf = *(volatile const int*)(ws + OFF_FLAG);
  if (bf) proj2_body((const ushort*)Wq, (const ushort*)Wk, (const ushort*)Wpi, (const ushort*)bpi,
                     (const ushort*)Wpj, (const ushort*)bpj, (const ushort*)Wd, (const ushort*)bd, ws);
  else    proj2_body((const float*)Wq, (const float*)Wk, (const float*)Wpi, (const float*)bpi,
                     (const float*)Wpj, (const float*)bpj, (const float*)Wd, (const float*)bd, ws);
}

// ---------------------------------------------------------------------------
// Kernel D-bf16: MFMA score assembly. 4 waves/block, each wave a 16x16
// quadrant of the 32x32 output tile. A/B fragments load directly from global
// (contiguous 16B per lane) — no LDS staging at all.
// ---------------------------------------------------------------------------
__global__ __launch_bounds__(256) void score_bf16_kernel(
    const void* __restrict__ xy, const float* __restrict__ ws,
    void* __restrict__ out)
{
  if (*(volatile const int*)(ws + OFF_FLAG) == 0) return;
  const int b  = blockIdx.z;
  const int n0 = blockIdx.y * 32, m0 = blockIdx.x * 32;
  const int tid = threadIdx.x;

  __shared__ float xyn[32][2], xym[32][2], dn[32];
  if (tid < 32) {
    const ushort* p = (const ushort*)xy;
    xyn[tid][0] = cvt(p[((b*N_) + n0 + tid)*2 + 0]);
    xyn[tid][1] = cvt(p[((b*N_) + n0 + tid)*2 + 1]);
    xym[tid][0] = cvt(p[((b*N_) + m0 + tid)*2 + 0]);
    xym[tid][1] = cvt(p[((b*N_) + m0 + tid)*2 + 1]);
    dn[tid] = ws[OFF_D + b*N_ + n0 + tid];
  }
  __syncthreads();

  const int w  = tid >> 6, l = tid & 63;
  const int wr = w >> 1, wc = w & 1;      // wave quadrant (2x2 of 16x16)
  const int lr = l & 15, lk = l >> 4;     // frag row/col, k-group

  const ushort* Qg = (const ushort*)(ws + OFF_Q)
      + ((size_t)(b*N_) + n0 + wr*16 + lr) * QK2W_ + lk*8;
  const ushort* Kg = (const ushort*)(ws + OFF_K)
      + ((size_t)(b*N_) + m0 + wc*16 + lr) * QK2W_ + lk*8;

  f32x4 acc = {0.f, 0.f, 0.f, 0.f};
  #pragma unroll
  for (int kc = 0; kc < 7; ++kc) {
    short8v av = *(const short8v*)(Qg + kc*32);
    short8v bv = *(const short8v*)(Kg + kc*32);
    acc = __builtin_amdgcn_mfma_f32_16x16x32_bf16(av, bv, acc, 0, 0, 0);
  }
  // acc now = HEAD_SCALE*QK^T + alpha_pair * a_i.b_j
  // lane l, reg r -> row (wr*16 + lk*4 + r), col (wc*16 + lr)   [m89 layout]

  const float c0 = ws[OFF_CS + 2*b], s0 = ws[OFF_CS + 2*b + 1];
  const float* wsm = ws + OFF_W;
  const float bg2v = wsm[640], ba2v = wsm[641];
  const float ag = wsm[643], aa = wsm[644], ls = wsm[645];

  const int ml = wc*16 + lr;              // col within 32-tile (fixed per lane)
  const float ym = xym[ml][0], xm = xym[ml][1];

  const float STEP  = 1.41421354f / 7.0f;
  const float GAMMA = 1.0f / (2.0f*STEP*STEP + 1e-8f);
  float C1[4], S1[4], C2[4], S2[4], C4v[4], S4[4], DY[4], DX[4], PHI[4][8];
  #pragma unroll
  for (int r = 0; r < 4; ++r) {
    const int nl_ = wr*16 + lk*4 + r;     // row within 32-tile
    float dy = xyn[nl_][0] - ym, dx = xyn[nl_][1] - xm;
    DY[r] = dy; DX[r] = dx;
    float h2 = fmaf(dx, dx, dy*dy);
    float rr = sqrtf(h2 + 1e-8f);
    float ct, st;
    if (h2 > 0.f) { float ih = 1.0f / sqrtf(h2); ct = dx*ih; st = dy*ih; }
    else          { ct = 1.f; st = 0.f; }             // atan2(0,0)=0
    float c1 = ct*c0 + st*s0;                         // cos(theta - theta0)
    float s1 = st*c0 - ct*s0;                         // sin(theta - theta0)
    C1[r] = c1; S1[r] = s1;
    float c2 = c1*c1 - s1*s1, s2 = 2.f*c1*s1;
    C2[r] = c2; S2[r] = s2;
    C4v[r] = c2*c2 - s2*s2; S4[r] = 2.f*c2*s2;
    #pragma unroll
    for (int k = 0; k < 8; ++k) {
      float d = rr - (float)k * STEP;
      PHI[r][k] = __expf(-GAMMA * d * d);
    }
  }

  // G MLP: 12 -> 32 -> 1 (weights via uniform scalar loads)
  float g[4] = {0,0,0,0};
  #pragma unroll 4
  for (int j = 0; j < 32; ++j) {
    const float* wj = wsm + j*16;
    #pragma unroll
    for (int r = 0; r < 4; ++r) {
      float h = fmaf(DY[r], wj[0], fmaf(DX[r], wj[1], wj[12]));
      #pragma unroll
      for (int k = 0; k < 8; ++k) h = fmaf(PHI[r][k], wj[2+k], h);
      h = fmaf(C1[r], wj[10], fmaf(S1[r], wj[11], h));
      g[r] = fmaf(fmaxf(h, 0.f), wj[13], g[r]);
    }
  }

  // angle MLP: 6 -> 16 -> 1
  float hb[4] = {0,0,0,0};
  #pragma unroll 4
  for (int j = 0; j < 16; ++j) {
    const float* wj = wsm + 512 + j*8;
    #pragma unroll
    for (int r = 0; r < 4; ++r) {
      float h = fmaf(C1[r],  wj[0], fmaf(S1[r], wj[1], wj[6]));
      h = fmaf(C2[r],  wj[2], fmaf(S2[r], wj[3], h));
      h = fmaf(C4v[r], wj[4], fmaf(S4[r], wj[5], h));
      hb[r] = fmaf(fmaxf(h, 0.f), wj[7], hb[r]);
    }
  }

  const int m_g = m0 + ml;
  #pragma unroll
  for (int r = 0; r < 4; ++r) {
    const int nl_ = wr*16 + lk*4 + r;
    const int n_g = n0 + nl_;
    float S = acc[r] + ag*(g[r] + bg2v) + aa*(hb[r] + ba2v);
    if (n_g == m_g) S += dn[nl_];
    S *= ls;
    ((__hip_bfloat16*)out)[((size_t)(b*N_) + n_g)*N_ + m_g] = __float2bfloat16(S);
  }
}

// ---------------------------------------------------------------------------
// Kernel D-f32: original VALU score assembly (f32 input mode only)
// ---------------------------------------------------------------------------
__global__ __launch_bounds__(256, 2) void score_f32_kernel(
    const void* __restrict__ xy, const float* __restrict__ ws,
    void* __restrict__ out)
{
  if (*(volatile const int*)(ws + OFF_FLAG) != 0) return;
  const int b  = blockIdx.z;
  const int n0 = blockIdx.y * 32, m0 = blockIdx.x * 32;
  const int tid = threadIdx.x;

  __shared__ float Qt[32][196];   // pad 192->196: rows land on distinct banks
  __shared__ float Kt[32][196];
  __shared__ float At[32][20];    // pad 16->20
  __shared__ float Bt[32][20];
  __shared__ float xyn[32][2], xym[32][2], dn[32];

  const float* Qg = ws + OFF_Q + ((size_t)(b*N_) + n0) * HR_;
  const float* Kg = ws + OFF_K + ((size_t)(b*N_) + m0) * HR_;
  for (int i = tid; i < 1536; i += 256) {
    int row = i / 48, c = (i % 48) * 4;
    *(float4*)&Qt[row][c] = *(const float4*)(Qg + row*HR_ + c);
    *(float4*)&Kt[row][c] = *(const float4*)(Kg + row*HR_ + c);
  }
  const float* Ag = ws + OFF_A  + ((size_t)(b*N_) + n0) * PH_;
  const float* Bg = ws + OFF_BJ + ((size_t)(b*N_) + m0) * PH_;
  for (int i = tid; i < 128; i += 256) {
    int row = i / 4, c = (i % 4) * 4;
    *(float4*)&At[row][c] = *(const float4*)(Ag + row*PH_ + c);
    *(float4*)&Bt[row][c] = *(const float4*)(Bg + row*PH_ + c);
  }
  {
    const float* p = (const float*)xy;
    if (tid < 32) {
      xyn[tid][0] = p[((b*N_) + n0 + tid)*2 + 0];
      xyn[tid][1] = p[((b*N_) + n0 + tid)*2 + 1];
      xym[tid][0] = p[((b*N_) + m0 + tid)*2 + 0];
      xym[tid][1] = p[((b*N_) + m0 + tid)*2 + 1];
      dn[tid] = ws[OFF_D + b*N_ + n0 + tid];
    }
  }
  __syncthreads();

  const float c0 = ws[OFF_CS + 2*b], s0 = ws[OFF_CS + 2*b + 1];
  const float* wsm = ws + OFF_W;
  const float bg2v = wsm[640], ba2v = wsm[641];
  const float ap = wsm[642], ag = wsm[643], aa = wsm[644], ls = wsm[645];

  const int nl = tid >> 3, mg = tid & 7;   // thread: row nl, 4 cols mg+8p

  float accQ[4] = {0,0,0,0}, accP[4] = {0,0,0,0};
  #pragma unroll 4
  for (int c = 0; c < HR_; c += 4) {
    float4 q = *(const float4*)&Qt[nl][c];
    #pragma unroll
    for (int p = 0; p < 4; ++p) {
      float4 k = *(const float4*)&Kt[mg + 8*p][c];
      accQ[p] = fmaf(q.x,k.x, fmaf(q.y,k.y, fmaf(q.z,k.z, fmaf(q.w,k.w, accQ[p]))));
    }
  }
  #pragma unroll
  for (int c = 0; c < PH_; c += 4) {
    float4 a = *(const float4*)&At[nl][c];
    #pragma unroll
    for (int p = 0; p < 4; ++p) {
      float4 v = *(const float4*)&Bt[mg + 8*p][c];
      accP[p] = fmaf(a.x,v.x, fmaf(a.y,v.y, fmaf(a.z,v.z, fmaf(a.w,v.w, accP[p]))));
    }
  }

  const float STEP  = 1.41421354f / 7.0f;
  const float GAMMA = 1.0f / (2.0f*STEP*STEP + 1e-8f);
  const float yn = xyn[nl][0], xn = xyn[nl][1];
  float DY[4], DX[4], C1[4], S1[4], C2[4], S2[4], C4v[4], S4[4], PHI[4][8];
  #pragma unroll
  for (int p = 0; p < 4; ++p) {
    int ml = mg + 8*p;
    float dy = yn - xym[ml][0], dx = xn - xym[ml][1];
    DY[p] = dy; DX[p] = dx;
    float h2 = fmaf(dx, dx, dy*dy);
    float r = sqrtf(h2 + 1e-8f);
    float ct, st;
    if (h2 > 0.f) { float ih = 1.0f / sqrtf(h2); ct = dx*ih; st = dy*ih; }
    else          { ct = 1.f; st = 0.f; }
    float c1 = ct*c0 + st*s0;
    float s1 = st*c0 - ct*s0;
    C1[p] = c1; S1[p] = s1;
    float c2 = c1*c1 - s1*s1, s2 = 2.f*c1*s1;
    C2[p] = c2; S2[p] = s2;
    C4v[p] = c2*c2 - s2*s2; S4[p] = 2.f*c2*s2;
    #pragma unroll
    for (int k = 0; k < 8; ++k) {
      float d = r - (float)k * STEP;
      PHI[p][k] = __expf(-GAMMA * d * d);
    }
  }

  float g[4] = {0,0,0,0};
  #pragma unroll 4
  for (int j = 0; j < 32; ++j) {
    const float* wj = wsm + j*16;
    #pragma unroll
    for (int p = 0; p < 4; ++p) {
      float h = fmaf(DY[p], wj[0], fmaf(DX[p], wj[1], wj[12]));
      #pragma unroll
      for (int k = 0; k < 8; ++k) h = fmaf(PHI[p][k], wj[2+k], h);
      h = fmaf(C1[p], wj[10], fmaf(S1[p], wj[11], h));
      g[p] = fmaf(fmaxf(h, 0.f), wj[13], g[p]);
    }
  }

  float hb[4] = {0,0,0,0};
  #pragma unroll 4
  for (int j = 0; j < 16; ++j) {
    const float* wj = wsm + 512 + j*8;
    #pragma unroll
    for (int p = 0; p < 4; ++p) {
      float h = fmaf(C1[p],  wj[0], fmaf(S1[p], wj[1], wj[6]));
      h = fmaf(C2[p],  wj[2], fmaf(S2[p], wj[3], h));
      h = fmaf(C4v[p], wj[4], fmaf(S4[p], wj[5], h));
      hb[p] = fmaf(fmaxf(h, 0.f), wj[7], hb[p]);
    }
  }

  const int n_g = n0 + nl;
  #pragma unroll
  for (int p = 0; p < 4; ++p) {
    const int m_g = m0 + mg + 8*p;
    float S = HEAD_SCALE_*accQ[p] + ap*accP[p] + ag*(g[p] + bg2v) + aa*(hb[p] + ba2v);
    if (n_g == m_g) S += dn[nl];
    S *= ls;
    ((float*)out)[((size_t)(b*N_) + n_g)*N_ + m_g] = S;
  }
}

// ---------------------------------------------------------------------------
// Host: replicate jax.random.normal(key(42), (8,2,1)) — threefry2x32
// (partitionable mode) + XLA/Giles f32 erfinv.
// ---------------------------------------------------------------------------
static inline uint32_t rotl32(uint32_t x, int d) { return (x << d) | (x >> (32 - d)); }

static void threefry2x32_host(uint32_t k0, uint32_t k1, uint32_t& x0, uint32_t& x1) {
  const uint32_t ks0 = k0, ks1 = k1, ks2 = k0 ^ k1 ^ 0x1BD11BDAu;
  static const int R[2][4] = {{13,15,26,6},{17,29,16,24}};
  x0 += ks0; x1 += ks1;
  const uint32_t ks[3] = {ks0, ks1, ks2};
  for (int i = 0; i < 5; ++i) {
    const int* r = R[i & 1];
    for (int j = 0; j < 4; ++j) { x0 += x1; x1 = rotl32(x1, r[j]); x1 ^= x0; }
    x0 += ks[(i + 1) % 3];
    x1 += ks[(i + 2) % 3] + (uint32_t)(i + 1);
  }
}

static float erfinv_host(float x) {
  float w = -log1pf(-x * x);
  float p;
  if (w < 5.0f) {
    w = w - 2.5f;
    p = 2.81022636e-08f;
    p = fmaf(p, w, 3.43273939e-07f);
    p = fmaf(p, w, -3.5233877e-06f);
    p = fmaf(p, w, -4.39150654e-06f);
    p = fmaf(p, w, 0.00021858087f);
    p = fmaf(p, w, -0.00125372503f);
    p = fmaf(p, w, -0.00417768164f);
    p = fmaf(p, w, 0.246640727f);
    p = fmaf(p, w, 1.50140941f);
  } else {
    w = sqrtf(w) - 3.0f;
    p = -0.000200214257f;
    p = fmaf(p, w, 0.000100950558f);
    p = fmaf(p, w, 0.00134934322f);
    p = fmaf(p, w, -0.00367342844f);
    p = fmaf(p, w, 0.00573950773f);
    p = fmaf(p, w, -0.0076224613f);
    p = fmaf(p, w, 0.00943887047f);
    p = fmaf(p, w, 1.00167406f);
    p = fmaf(p, w, 2.83297682f);
  }
  return p * x;
}

static VInit make_vinit() {
  VInit vi;
  for (int i = 0; i < 16; ++i) {
    uint32_t o0 = 0u, o1 = (uint32_t)i;
    threefry2x32_host(0u, 42u, o0, o1);
    uint32_t bits = o0 ^ o1;
    uint32_t fb = (bits >> 9) | 0x3f800000u;
    float f; memcpy(&f, &fb, 4); f -= 1.0f;
    const float lo = -0.99999994f;
    float u = f * 2.0f + lo;
    if (u < lo) u = lo;
    vi.v[i] = 1.41421354f * erfinv_host(u);
  }
  return vi;
}

// ---------------------------------------------------------------------------
extern "C" void kernel_launch(void* const* d_in, const int* in_sizes, int n_in,
                              void* d_out, int out_size, void* d_ws, size_t ws_size,
                              hipStream_t stream) {
  (void)in_sizes; (void)n_in; (void)out_size;
  if (ws_size < (size_t)WS_FLOATS * sizeof(float)) return;

  const void* feats = d_in[0];
  const void* xy    = d_in[1];
  const void* Wq    = d_in[2];
  const void* Wk    = d_in[3];
  const void* Wpi   = d_in[4];
  const void* bpi   = d_in[5];
  const void* Wpj   = d_in[6];
  const void* bpj   = d_in[7];
  const void* apair = d_in[8];
  const void* Wg1   = d_in[9];
  const void* bg1   = d_in[10];
  const void* bg2w  = d_in[11];  // Wg2
  const void* bg2b  = d_in[12];  // bg2
  const void* ageom = d_in[13];
  const void* Wa1   = d_in[14];
  const void* ba1   = d_in[15];
  const void* Wa2   = d_in[16];
  const void* ba2   = d_in[17];
  const void* aang  = d_in[18];
  const void* Wd    = d_in[19];
  const void* bd    = d_in[20];
  const void* lsc   = d_in[21];
  float* ws = (float*)d_ws;

  VInit vi = make_vinit();

  hipLaunchKernelGGL(detect_kernel, dim3(1), dim3(64), 0, stream,
      (const uint32_t*)Wg1, ws);
  hipLaunchKernelGGL(prep_kernel, dim3(B_), dim3(256), 0, stream,
      xy, Wg1, bg1, bg2w, bg2b, Wa1, ba1, Wa2, ba2, apair, ageom, aang, lsc, ws, vi);
  hipLaunchKernelGGL(fold_kernel, dim3(1536), dim3(256), 0, stream, feats, ws);
  hipLaunchKernelGGL(proj_kernel, dim3(7, 64), dim3(256), 0, stream,
      Wq, Wk, Wpi, bpi, Wpj, bpj, Wd, bd, ws);
  hipLaunchKernelGGL(score_bf16_kernel, dim3(16, 16, B_), dim3(256), 0, stream,
      xy, ws, d_out);
  hipLaunchKernelGGL(score_f32_kernel, dim3(16, 16, B_), dim3(256), 0, stream,
      xy, ws, d_out);
}

// Round 3
// 201.194 us; speedup vs baseline: 1.5483x; 1.1035x over previous
//
#include <hip/hip_runtime.h>
#include <hip/hip_bf16.h>
#include <stdint.h>
#include <string.h>
#include <math.h>

// Problem constants
#define B_ 8
#define N_ 512
#define C_ 384
#define HR_ 192          // H*R = 6*32
#define PH_ 16           // PAIR_HIDDEN
#define HEAD_SCALE_ 0.17677669529663687f
#define QK2W_ 224        // packed row: 192 Q/K | 16 pair | 16 zero  (7 x K=32)

// Workspace layout (float offsets)
// Q2/K2 are hi/lo bf16 pairs: S = Qhi.Khi + Qhi.Klo + Qlo.Khi reconstructs
// the f32 bilinear form to ~2^-18 relative (lo.lo dropped).
#define QK2SZF  (B_*N_*QK2W_/2)              // 458752 floats per bf16 array
#define OFF_X    0
#define OFF_Q2   (B_*N_*C_)                  // 1572864
#define OFF_Q2L  (OFF_Q2  + QK2SZF)
#define OFF_K2   (OFF_Q2L + QK2SZF)
#define OFF_K2L  (OFF_K2  + QK2SZF)
#define OFF_D    (OFF_K2L + QK2SZF)
#define OFF_CS   (OFF_D + B_*N_)
#define OFF_W    (OFF_CS + 2*B_)
#define OFF_FLAG (OFF_W + 700)               // int: 1 = inputs are bf16, 0 = f32
#define WS_FLOATS (OFF_W + 768)

struct VInit { float v[16]; };

typedef __attribute__((ext_vector_type(8))) short short8v;
typedef __attribute__((ext_vector_type(4))) float f32x4;

__device__ __forceinline__ float cvt(ushort u) {
  union { uint32_t i; float f; } x; x.i = ((uint32_t)u) << 16; return x.f;
}
__device__ __forceinline__ float cvt(float f) { return f; }

__device__ __forceinline__ ushort f2bf(float f) {
  __hip_bfloat16 h = __float2bfloat16(f);
  union { __hip_bfloat16 b; ushort u; } x; x.b = h; return x.u;
}

__device__ __forceinline__ float4 ld4v(const ushort* p) {
  ushort4 u = *(const ushort4*)p;
  return make_float4(cvt(u.x), cvt(u.y), cvt(u.z), cvt(u.w));
}
__device__ __forceinline__ float4 ld4v(const float* p) { return *(const float4*)p; }

// ---------------------------------------------------------------------------
// Kernel 0: dtype detection. If Wg1 holds bf16, the low ushort of each dword
// decodes to a sane-magnitude bf16 (N(0,0.3) weights). If it holds f32, the
// low 16 bits are uniform mantissa bits (sane-decode prob ~10%). 128 dwords
// are valid to read under both layouts (512 B <= min(768, 1536) B).
// ---------------------------------------------------------------------------
__global__ void detect_kernel(const uint32_t* __restrict__ wg1, float* __restrict__ ws) {
  if (threadIdx.x == 0 && blockIdx.x == 0) {
    int cnt = 0;
    for (int i = 0; i < 128; ++i) {
      uint32_t d = wg1[i];
      float v = cvt((ushort)(d & 0xFFFFu));
      float av = fabsf(v);
      if (av == 0.0f || (av >= 9.5367431640625e-07f && av <= 32.0f)) ++cnt;
    }
    *(int*)(ws + OFF_FLAG) = (cnt >= 64) ? 1 : 0;
  }
}

// ---------------------------------------------------------------------------
// Weight tables (transposed for uniform scalar loads in score kernel)
// ---------------------------------------------------------------------------
template <typename T>
__device__ void build_tables(const T* Wg1, const T* bg1, const T* Wg2, const T* bg2,
                             const T* Wa1, const T* ba1, const T* Wa2, const T* ba2,
                             const T* apair, const T* ageom, const T* aang, const T* lsc,
                             float* ws, int tid) {
  for (int j = tid; j < 32; j += 256) {
    float* wj = ws + OFF_W + j*16;
    #pragma unroll
    for (int i = 0; i < 12; ++i) wj[i] = cvt(Wg1[i*32 + j]);
    wj[12] = cvt(bg1[j]);
    wj[13] = cvt(Wg2[j]);
    wj[14] = 0.f; wj[15] = 0.f;
  }
  for (int j = tid; j < 16; j += 256) {
    float* wj = ws + OFF_W + 512 + j*8;
    #pragma unroll
    for (int i = 0; i < 6; ++i) wj[i] = cvt(Wa1[i*16 + j]);
    wj[6] = cvt(ba1[j]);
    wj[7] = cvt(Wa2[j]);
  }
  if (tid == 0) {
    ws[OFF_W + 640] = cvt(bg2[0]);
    ws[OFF_W + 641] = cvt(ba2[0]);
    ws[OFF_W + 642] = fmaxf(cvt(apair[0]), 0.f);
    ws[OFF_W + 643] = fmaxf(cvt(ageom[0]), 0.f);
    ws[OFF_W + 644] = fmaxf(cvt(aang[0]), 0.f);
    ws[OFF_W + 645] = fmaxf(cvt(lsc[0]), 0.01f);
  }
}

// ---------------------------------------------------------------------------
// Kernel A: per-batch principal orientation (power iteration) + weight tables
// ---------------------------------------------------------------------------
__global__ __launch_bounds__(256) void prep_kernel(
    const void* __restrict__ xy,
    const void* __restrict__ Wg1, const void* __restrict__ bg1,
    const void* __restrict__ Wg2, const void* __restrict__ bg2,
    const void* __restrict__ Wa1, const void* __restrict__ ba1,
    const void* __restrict__ Wa2, const void* __restrict__ ba2,
    const void* __restrict__ apair, const void* __restrict__ ageom,
    const void* __restrict__ aang, const void* __restrict__ lsc,
    float* __restrict__ ws, VInit vi)
{
  const int b = blockIdx.x, tid = threadIdx.x;
  const int bf = *(volatile const int*)(ws + OFF_FLAG);
  __shared__ float sxy[N_*2];
  __shared__ float red[256][4];

  if (bf) {
    const ushort* p = (const ushort*)xy + b*N_*2;
    for (int i = tid; i < N_*2; i += 256) sxy[i] = cvt(p[i]);
  } else {
    const float* p = (const float*)xy + b*N_*2;
    for (int i = tid; i < N_*2; i += 256) sxy[i] = p[i];
  }
  __syncthreads();

  // pass 1: mean
  float sy = 0.f, sx = 0.f;
  for (int i = tid; i < N_; i += 256) { sy += sxy[2*i]; sx += sxy[2*i+1]; }
  red[tid][0] = sy; red[tid][1] = sx;
  __syncthreads();
  for (int s = 128; s > 0; s >>= 1) {
    if (tid < s) { red[tid][0] += red[tid+s][0]; red[tid][1] += red[tid+s][1]; }
    __syncthreads();
  }
  const float my = red[0][0] / 512.0f;
  const float mx = red[0][1] / 512.0f;
  __syncthreads();

  // pass 2: covariance
  float c00 = 0.f, c01 = 0.f, c11 = 0.f;
  for (int i = tid; i < N_; i += 256) {
    float y = sxy[2*i] - my;
    float x = sxy[2*i+1] - mx;
    c00 += y*y; c01 += y*x; c11 += x*x;
  }
  red[tid][0] = c00; red[tid][1] = c01; red[tid][2] = c11;
  __syncthreads();
  for (int s = 128; s > 0; s >>= 1) {
    if (tid < s) {
      red[tid][0] += red[tid+s][0];
      red[tid][1] += red[tid+s][1];
      red[tid][2] += red[tid+s][2];
    }
    __syncthreads();
  }
  if (tid == 0) {
    float C00 = red[0][0] / 512.0f, C01 = red[0][1] / 512.0f, C11 = red[0][2] / 512.0f;
    float v0 = vi.v[2*b], v1 = vi.v[2*b + 1];
    float nr = sqrtf(v0*v0 + v1*v1) + 1e-8f; v0 /= nr; v1 /= nr;
    for (int it = 0; it < 5; ++it) {
      float w0 = C00*v0 + C01*v1;
      float w1 = C01*v0 + C11*v1;
      nr = sqrtf(w0*w0 + w1*w1) + 1e-8f;
      v0 = w0/nr; v1 = w1/nr;
    }
    float h = sqrtf(v0*v0 + v1*v1);
    ws[OFF_CS + 2*b + 0] = v0 / h;   // cos(theta0)
    ws[OFF_CS + 2*b + 1] = v1 / h;   // sin(theta0)
  }

  if (b == 0) {
    if (bf) build_tables((const ushort*)Wg1, (const ushort*)bg1, (const ushort*)Wg2, (const ushort*)bg2,
                         (const ushort*)Wa1, (const ushort*)ba1, (const ushort*)Wa2, (const ushort*)ba2,
                         (const ushort*)apair, (const ushort*)ageom, (const ushort*)aang, (const ushort*)lsc,
                         ws, tid);
    else    build_tables((const float*)Wg1, (const float*)bg1, (const float*)Wg2, (const float*)bg2,
                         (const float*)Wa1, (const float*)ba1, (const float*)Wa2, (const float*)ba2,
                         (const float*)apair, (const float*)ageom, (const float*)aang, (const float*)lsc,
                         ws, tid);
  }
}

// ---------------------------------------------------------------------------
// Kernel B: fold vertices -> x (f32)
// ---------------------------------------------------------------------------
template <typename T>
__device__ __forceinline__ void fold_body(const T* feats, float* ws, int idx) {
  const int c4 = idx % 96;
  const int bn = idx / 96;
  const int n = bn & (N_ - 1), b = bn >> 9;
  const T* r1 = feats + ((size_t)(b*(2*N_+1) + 1 + 2*n))*C_ + c4*4;
  float4 a = ld4v(r1);
  float4 c = ld4v(r1 + C_);
  float4 o;
  o.x = 0.5f*(a.x + c.x); o.y = 0.5f*(a.y + c.y);
  o.z = 0.5f*(a.z + c.z); o.w = 0.5f*(a.w + c.w);
  *(float4*)(ws + OFF_X + (size_t)idx*4) = o;
}

__global__ __launch_bounds__(256) void fold_kernel(const void* __restrict__ feats,
                                                   float* __restrict__ ws) {
  const int idx = blockIdx.x * 256 + threadIdx.x;
  const int bf = *(volatile const int*)(ws + OFF_FLAG);
  if (bf) fold_body((const ushort*)feats, ws, idx);
  else    fold_body((const float*)feats, ws, idx);
}

// ---------------------------------------------------------------------------
// Kernel C: LDS-tiled register-blocked f32 GEMM for all projections.
//   Grid: (7 col-tiles, 64 row-tiles). Block 256 threads = 64x64 output tile,
//   each thread a 4x4 register tile. Col-tiles 0-2 -> Wq, 3-5 -> Wk,
//   6 -> [Wpi | Wpj | Wd | zero-pad] with bias+relu epilogue.
//   Epilogue (BOTH dtypes) packs hi/lo bf16 rows (width 224):
//     Q2 = [HEAD_SCALE*Q | alpha_pair*relu(x@Wpi+bpi) | 0]   (hi + lo arrays)
//     K2 = [K            | relu(x@Wpj+bpj)            | 0]
//   so the score MFMA reconstructs the f32 bilinear form via 3-term split.
// ---------------------------------------------------------------------------
#define PKC 32
#define PNKS (C_/PKC)   // 12
#define PLDW 68

template <typename T>
__device__ __forceinline__ float4 load_w_small(const T* Wpi, const T* Wpj,
                                               const T* Wd, int c, int wcq) {
  float v[4];
  #pragma unroll
  for (int k = 0; k < 4; ++k) {
    int col = wcq*4 + k;
    float f = 0.f;
    if (col < 16)      f = cvt(Wpi[c*PH_ + col]);
    else if (col < 32) f = cvt(Wpj[c*PH_ + (col - 16)]);
    else if (col == 32) f = cvt(Wd[c]);
    v[k] = f;
  }
  return make_float4(v[0], v[1], v[2], v[3]);
}

__device__ __forceinline__ void split_bf(float v, ushort& hi, ushort& lo) {
  hi = f2bf(v);
  lo = f2bf(v - cvt(hi));
}

template <typename T>
__device__ void proj2_body(const T* __restrict__ Wq, const T* __restrict__ Wk,
                           const T* __restrict__ Wpi, const T* __restrict__ bpi,
                           const T* __restrict__ Wpj, const T* __restrict__ bpj,
                           const T* __restrict__ Wd,  const T* __restrict__ bd,
                           float* __restrict__ ws)
{
  const int ct  = blockIdx.x;      // 0..6
  const int rt  = blockIdx.y;      // 0..63
  const int tid = threadIdx.x;
  const int row0 = rt * 64;

  __shared__ float lx[PKC][PLDW];
  __shared__ float lw[PKC][PLDW];

  const float* X = ws + OFF_X + (size_t)row0 * C_;

  const bool sm = (ct == 6);
  const T* Wsrc = (ct < 3) ? Wq : Wk;
  const int col0 = (ct < 3) ? ct * 64 : (ct - 3) * 64;

  // staging thread mapping
  const int xrow = tid >> 3, xcq = tid & 7;    // x: 32 rows x 8 float4-chunks; 2 row-halves
  const int wc   = tid >> 4, wcq = tid & 15;   // w: 16 c x 16 float4-chunks; 2 c-halves
  // compute thread mapping
  const int tr = tid >> 4, tc = tid & 15;      // 4x4 tile at rows tr*4, cols tc*4

  float4 px0, px1, pw0, pw1;

  // prologue: prefetch k-chunk 0
  px0 = *(const float4*)(X + (size_t)(xrow     ) * C_ + xcq*4);
  px1 = *(const float4*)(X + (size_t)(xrow + 32) * C_ + xcq*4);
  if (!sm) {
    pw0 = ld4v(Wsrc + (size_t)(wc     ) * HR_ + col0 + wcq*4);
    pw1 = ld4v(Wsrc + (size_t)(wc + 16) * HR_ + col0 + wcq*4);
  } else {
    pw0 = load_w_small(Wpi, Wpj, Wd, wc,      wcq);
    pw1 = load_w_small(Wpi, Wpj, Wd, wc + 16, wcq);
  }

  float acc[4][4] = {{0,0,0,0},{0,0,0,0},{0,0,0,0},{0,0,0,0}};

  for (int ks = 0; ks < PNKS; ++ks) {
    // commit staged registers to LDS
    lx[xcq*4+0][xrow]      = px0.x;
    lx[xcq*4+1][xrow]      = px0.y;
    lx[xcq*4+2][xrow]      = px0.z;
    lx[xcq*4+3][xrow]      = px0.w;
    lx[xcq*4+0][xrow + 32] = px1.x;
    lx[xcq*4+1][xrow + 32] = px1.y;
    lx[xcq*4+2][xrow + 32] = px1.z;
    lx[xcq*4+3][xrow + 32] = px1.w;
    *(float4*)&lw[wc     ][wcq*4] = pw0;
    *(float4*)&lw[wc + 16][wcq*4] = pw1;
    __syncthreads();

    // prefetch next k-chunk into registers (hides under compute below)
    if (ks + 1 < PNKS) {
      const int c0 = (ks + 1) * PKC;
      px0 = *(const float4*)(X + (size_t)(xrow     ) * C_ + c0 + xcq*4);
      px1 = *(const float4*)(X + (size_t)(xrow + 32) * C_ + c0 + xcq*4);
      if (!sm) {
        pw0 = ld4v(Wsrc + (size_t)(c0 + wc     ) * HR_ + col0 + wcq*4);
        pw1 = ld4v(Wsrc + (size_t)(c0 + wc + 16) * HR_ + col0 + wcq*4);
      } else {
        pw0 = load_w_small(Wpi, Wpj, Wd, c0 + wc,      wcq);
        pw1 = load_w_small(Wpi, Wpj, Wd, c0 + wc + 16, wcq);
      }
    }

    // 4x4 register-tile FMA over the staged chunk
    #pragma unroll
    for (int c = 0; c < PKC; ++c) {
      float4 xv = *(const float4*)&lx[c][tr*4];   // 4 rows (broadcast across tc)
      float4 wv = *(const float4*)&lw[c][tc*4];   // 4 cols (2-way bank, free)
      acc[0][0] = fmaf(xv.x, wv.x, acc[0][0]);
      acc[0][1] = fmaf(xv.x, wv.y, acc[0][1]);
      acc[0][2] = fmaf(xv.x, wv.z, acc[0][2]);
      acc[0][3] = fmaf(xv.x, wv.w, acc[0][3]);
      acc[1][0] = fmaf(xv.y, wv.x, acc[1][0]);
      acc[1][1] = fmaf(xv.y, wv.y, acc[1][1]);
      acc[1][2] = fmaf(xv.y, wv.z, acc[1][2]);
      acc[1][3] = fmaf(xv.y, wv.w, acc[1][3]);
      acc[2][0] = fmaf(xv.z, wv.x, acc[2][0]);
      acc[2][1] = fmaf(xv.z, wv.y, acc[2][1]);
      acc[2][2] = fmaf(xv.z, wv.z, acc[2][2]);
      acc[2][3] = fmaf(xv.z, wv.w, acc[2][3]);
      acc[3][0] = fmaf(xv.w, wv.x, acc[3][0]);
      acc[3][1] = fmaf(xv.w, wv.y, acc[3][1]);
      acc[3][2] = fmaf(xv.w, wv.z, acc[3][2]);
      acc[3][3] = fmaf(xv.w, wv.w, acc[3][3]);
    }
    __syncthreads();
  }

  // epilogue: hi/lo bf16 packing (dtype-independent)
  ushort* q2h = (ushort*)(ws + OFF_Q2);
  ushort* q2l = (ushort*)(ws + OFF_Q2L);
  ushort* k2h = (ushort*)(ws + OFF_K2);
  ushort* k2l = (ushort*)(ws + OFF_K2L);

  if (!sm) {
    const float sc = (ct < 3) ? HEAD_SCALE_ : 1.0f;
    ushort* bh = (ct < 3) ? q2h : k2h;
    ushort* bl = (ct < 3) ? q2l : k2l;
    #pragma unroll
    for (int r = 0; r < 4; ++r) {
      const int row = row0 + tr*4 + r;
      ushort4 oh, ol;
      split_bf(sc*acc[r][0], oh.x, ol.x);
      split_bf(sc*acc[r][1], oh.y, ol.y);
      split_bf(sc*acc[r][2], oh.z, ol.z);
      split_bf(sc*acc[r][3], oh.w, ol.w);
      *(ushort4*)(bh + (size_t)row*QK2W_ + col0 + tc*4) = oh;
      *(ushort4*)(bl + (size_t)row*QK2W_ + col0 + tc*4) = ol;
    }
  } else {
    // zero the k=208..223 pad slots: 64 rows x 4 arrays x 32B (2 x uint4)
    {
      const int row = row0 + (tid & 63);
      ushort* arr = (tid < 64) ? q2h : (tid < 128) ? q2l : (tid < 192) ? k2h : k2l;
      uint4 z = make_uint4(0,0,0,0);
      *(uint4*)(arr + (size_t)row*QK2W_ + 208) = z;
      *(uint4*)(arr + (size_t)row*QK2W_ + 216) = z;
    }
    const float ap = ws[OFF_W + 642];
    #pragma unroll
    for (int r = 0; r < 4; ++r) {
      const int row = row0 + tr*4 + r;
      #pragma unroll
      for (int k = 0; k < 4; ++k) {
        const int col = tc*4 + k;
        if (col < 16) {
          float v = ap * fmaxf(acc[r][k] + cvt(bpi[col]), 0.f);
          ushort hi, lo; split_bf(v, hi, lo);
          q2h[(size_t)row*QK2W_ + 192 + col] = hi;
          q2l[(size_t)row*QK2W_ + 192 + col] = lo;
        } else if (col < 32) {
          float v = fmaxf(acc[r][k] + cvt(bpj[col - 16]), 0.f);
          ushort hi, lo; split_bf(v, hi, lo);
          k2h[(size_t)row*QK2W_ + 192 + (col - 16)] = hi;
          k2l[(size_t)row*QK2W_ + 192 + (col - 16)] = lo;
        } else if (col == 32) {
          ws[OFF_D + row] = acc[r][k] + cvt(bd[0]);
        }
      }
    }
  }
}

__global__ __launch_bounds__(256) void proj_kernel(
    const void* __restrict__ Wq, const void* __restrict__ Wk,
    const void* __restrict__ Wpi, const void* __restrict__ bpi,
    const void* __restrict__ Wpj, const void* __restrict__ bpj,
    const void* __restrict__ Wd,  const void* __restrict__ bd,
    float* __restrict__ ws)
{
  const int bf = *(volatile const int*)(ws + OFF_FLAG);
  if (bf) proj2_body((const ushort*)Wq, (const ushort*)Wk, (const ushort*)Wpi, (const ushort*)bpi,
                     (const ushort*)Wpj, (const ushort*)bpj, (const ushort*)Wd, (const ushort*)bd, ws);
  else    proj2_body((const float*)Wq, (const float*)Wk, (const float*)Wpi, (const float*)bpi,
                     (const float*)Wpj, (const float*)bpj, (const float*)Wd, (const float*)bd, ws);
}

// ---------------------------------------------------------------------------
// Kernel D (unified): MFMA score assembly. 4 waves/block, each wave a 16x16
// quadrant of the 32x32 output tile. A/B fragments load directly from global
// (contiguous 16B per lane) — no LDS staging. 3-term hi/lo split reconstructs
// the f32 bilinear part: acc = HEAD_SCALE*QK^T + alpha_pair*a_i.b_j.
// MLPs stay in f32 VALU. Only xy load + out store branch on dtype.
// ---------------------------------------------------------------------------
__global__ __launch_bounds__(256) void score_kernel(
    const void* __restrict__ xy, const float* __restrict__ ws,
    void* __restrict__ out)
{
  const int bf = *(volatile const int*)(ws + OFF_FLAG);
  const int b  = blockIdx.z;
  const int n0 = blockIdx.y * 32, m0 = blockIdx.x * 32;
  const int tid = threadIdx.x;

  __shared__ float xyn[32][2], xym[32][2], dn[32];
  if (tid < 32) {
    if (bf) {
      const ushort* p = (const ushort*)xy;
      xyn[tid][0] = cvt(p[((b*N_) + n0 + tid)*2 + 0]);
      xyn[tid][1] = cvt(p[((b*N_) + n0 + tid)*2 + 1]);
      xym[tid][0] = cvt(p[((b*N_) + m0 + tid)*2 + 0]);
      xym[tid][1] = cvt(p[((b*N_) + m0 + tid)*2 + 1]);
    } else {
      const float* p = (const float*)xy;
      xyn[tid][0] = p[((b*N_) + n0 + tid)*2 + 0];
      xyn[tid][1] = p[((b*N_) + n0 + tid)*2 + 1];
      xym[tid][0] = p[((b*N_) + m0 + tid)*2 + 0];
      xym[tid][1] = p[((b*N_) + m0 + tid)*2 + 1];
    }
    dn[tid] = ws[OFF_D + b*N_ + n0 + tid];
  }
  __syncthreads();

  const int w  = tid >> 6, l = tid & 63;
  const int wr = w >> 1, wc = w & 1;      // wave quadrant (2x2 of 16x16)
  const int lr = l & 15, lk = l >> 4;     // frag row/col, k-group

  const size_t qoff = ((size_t)(b*N_) + n0 + wr*16 + lr) * QK2W_ + lk*8;
  const size_t koff = ((size_t)(b*N_) + m0 + wc*16 + lr) * QK2W_ + lk*8;
  const ushort* qh = (const ushort*)(ws + OFF_Q2)  + qoff;
  const ushort* ql = (const ushort*)(ws + OFF_Q2L) + qoff;
  const ushort* kh = (const ushort*)(ws + OFF_K2)  + koff;
  const ushort* kl = (const ushort*)(ws + OFF_K2L) + koff;

  f32x4 acc = {0.f, 0.f, 0.f, 0.f};
  #pragma unroll
  for (int kc = 0; kc < 7; ++kc) {
    short8v ah = *(const short8v*)(qh + kc*32);
    short8v al = *(const short8v*)(ql + kc*32);
    short8v bh = *(const short8v*)(kh + kc*32);
    short8v bl = *(const short8v*)(kl + kc*32);
    acc = __builtin_amdgcn_mfma_f32_16x16x32_bf16(ah, bh, acc, 0, 0, 0);
    acc = __builtin_amdgcn_mfma_f32_16x16x32_bf16(ah, bl, acc, 0, 0, 0);
    acc = __builtin_amdgcn_mfma_f32_16x16x32_bf16(al, bh, acc, 0, 0, 0);
  }
  // lane l, reg r -> row (wr*16 + lk*4 + r), col (wc*16 + lr)   [m89 layout]

  const float c0 = ws[OFF_CS + 2*b], s0 = ws[OFF_CS + 2*b + 1];
  const float* wsm = ws + OFF_W;
  const float bg2v = wsm[640], ba2v = wsm[641];
  const float ag = wsm[643], aa = wsm[644], ls = wsm[645];

  const int ml = wc*16 + lr;              // col within 32-tile (fixed per lane)
  const float ym = xym[ml][0], xm = xym[ml][1];

  const float STEP  = 1.41421354f / 7.0f;
  const float GAMMA = 1.0f / (2.0f*STEP*STEP + 1e-8f);
  float C1[4], S1[4], C2[4], S2[4], C4v[4], S4[4], DY[4], DX[4], PHI[4][8];
  #pragma unroll
  for (int r = 0; r < 4; ++r) {
    const int nl_ = wr*16 + lk*4 + r;     // row within 32-tile
    float dy = xyn[nl_][0] - ym, dx = xyn[nl_][1] - xm;
    DY[r] = dy; DX[r] = dx;
    float h2 = fmaf(dx, dx, dy*dy);
    float rr = sqrtf(h2 + 1e-8f);
    float ct, st;
    if (h2 > 0.f) { float ih = 1.0f / sqrtf(h2); ct = dx*ih; st = dy*ih; }
    else          { ct = 1.f; st = 0.f; }             // atan2(0,0)=0
    float c1 = ct*c0 + st*s0;                         // cos(theta - theta0)
    float s1 = st*c0 - ct*s0;                         // sin(theta - theta0)
    C1[r] = c1; S1[r] = s1;
    float c2 = c1*c1 - s1*s1, s2 = 2.f*c1*s1;
    C2[r] = c2; S2[r] = s2;
    C4v[r] = c2*c2 - s2*s2; S4[r] = 2.f*c2*s2;
    #pragma unroll
    for (int k = 0; k < 8; ++k) {
      float d = rr - (float)k * STEP;
      PHI[r][k] = __expf(-GAMMA * d * d);
    }
  }

  // G MLP: 12 -> 32 -> 1 (weights via uniform scalar loads)
  float g[4] = {0,0,0,0};
  #pragma unroll 4
  for (int j = 0; j < 32; ++j) {
    const float* wj = wsm + j*16;
    #pragma unroll
    for (int r = 0; r < 4; ++r) {
      float h = fmaf(DY[r], wj[0], fmaf(DX[r], wj[1], wj[12]));
      #pragma unroll
      for (int k = 0; k < 8; ++k) h = fmaf(PHI[r][k], wj[2+k], h);
      h = fmaf(C1[r], wj[10], fmaf(S1[r], wj[11], h));
      g[r] = fmaf(fmaxf(h, 0.f), wj[13], g[r]);
    }
  }

  // angle MLP: 6 -> 16 -> 1
  float hb[4] = {0,0,0,0};
  #pragma unroll 4
  for (int j = 0; j < 16; ++j) {
    const float* wj = wsm + 512 + j*8;
    #pragma unroll
    for (int r = 0; r < 4; ++r) {
      float h = fmaf(C1[r],  wj[0], fmaf(S1[r], wj[1], wj[6]));
      h = fmaf(C2[r],  wj[2], fmaf(S2[r], wj[3], h));
      h = fmaf(C4v[r], wj[4], fmaf(S4[r], wj[5], h));
      hb[r] = fmaf(fmaxf(h, 0.f), wj[7], hb[r]);
    }
  }

  const int m_g = m0 + ml;
  #pragma unroll
  for (int r = 0; r < 4; ++r) {
    const int nl_ = wr*16 + lk*4 + r;
    const int n_g = n0 + nl_;
    float S = acc[r] + ag*(g[r] + bg2v) + aa*(hb[r] + ba2v);
    if (n_g == m_g) S += dn[nl_];
    S *= ls;
    const size_t oi = ((size_t)(b*N_) + n_g)*N_ + m_g;
    if (bf) ((__hip_bfloat16*)out)[oi] = __float2bfloat16(S);
    else    ((float*)out)[oi] = S;
  }
}

// ---------------------------------------------------------------------------
// Host: replicate jax.random.normal(key(42), (8,2,1)) — threefry2x32
// (partitionable mode) + XLA/Giles f32 erfinv.
// ---------------------------------------------------------------------------
static inline uint32_t rotl32(uint32_t x, int d) { return (x << d) | (x >> (32 - d)); }

static void threefry2x32_host(uint32_t k0, uint32_t k1, uint32_t& x0, uint32_t& x1) {
  const uint32_t ks0 = k0, ks1 = k1, ks2 = k0 ^ k1 ^ 0x1BD11BDAu;
  static const int R[2][4] = {{13,15,26,6},{17,29,16,24}};
  x0 += ks0; x1 += ks1;
  const uint32_t ks[3] = {ks0, ks1, ks2};
  for (int i = 0; i < 5; ++i) {
    const int* r = R[i & 1];
    for (int j = 0; j < 4; ++j) { x0 += x1; x1 = rotl32(x1, r[j]); x1 ^= x0; }
    x0 += ks[(i + 1) % 3];
    x1 += ks[(i + 2) % 3] + (uint32_t)(i + 1);
  }
}

static float erfinv_host(float x) {
  float w = -log1pf(-x * x);
  float p;
  if (w < 5.0f) {
    w = w - 2.5f;
    p = 2.81022636e-08f;
    p = fmaf(p, w, 3.43273939e-07f);
    p = fmaf(p, w, -3.5233877e-06f);
    p = fmaf(p, w, -4.39150654e-06f);
    p = fmaf(p, w, 0.00021858087f);
    p = fmaf(p, w, -0.00125372503f);
    p = fmaf(p, w, -0.00417768164f);
    p = fmaf(p, w, 0.246640727f);
    p = fmaf(p, w, 1.50140941f);
  } else {
    w = sqrtf(w) - 3.0f;
    p = -0.000200214257f;
    p = fmaf(p, w, 0.000100950558f);
    p = fmaf(p, w, 0.00134934322f);
    p = fmaf(p, w, -0.00367342844f);
    p = fmaf(p, w, 0.00573950773f);
    p = fmaf(p, w, -0.0076224613f);
    p = fmaf(p, w, 0.00943887047f);
    p = fmaf(p, w, 1.00167406f);
    p = fmaf(p, w, 2.83297682f);
  }
  return p * x;
}

static VInit make_vinit() {
  VInit vi;
  for (int i = 0; i < 16; ++i) {
    uint32_t o0 = 0u, o1 = (uint32_t)i;
    threefry2x32_host(0u, 42u, o0, o1);
    uint32_t bits = o0 ^ o1;
    uint32_t fb = (bits >> 9) | 0x3f800000u;
    float f; memcpy(&f, &fb, 4); f -= 1.0f;
    const float lo = -0.99999994f;
    float u = f * 2.0f + lo;
    if (u < lo) u = lo;
    vi.v[i] = 1.41421354f * erfinv_host(u);
  }
  return vi;
}

// ---------------------------------------------------------------------------
extern "C" void kernel_launch(void* const* d_in, const int* in_sizes, int n_in,
                              void* d_out, int out_size, void* d_ws, size_t ws_size,
                              hipStream_t stream) {
  (void)in_sizes; (void)n_in; (void)out_size;
  if (ws_size < (size_t)WS_FLOATS * sizeof(float)) return;

  const void* feats = d_in[0];
  const void* xy    = d_in[1];
  const void* Wq    = d_in[2];
  const void* Wk    = d_in[3];
  const void* Wpi   = d_in[4];
  const void* bpi   = d_in[5];
  const void* Wpj   = d_in[6];
  const void* bpj   = d_in[7];
  const void* apair = d_in[8];
  const void* Wg1   = d_in[9];
  const void* bg1   = d_in[10];
  const void* bg2w  = d_in[11];  // Wg2
  const void* bg2b  = d_in[12];  // bg2
  const void* ageom = d_in[13];
  const void* Wa1   = d_in[14];
  const void* ba1   = d_in[15];
  const void* Wa2   = d_in[16];
  const void* ba2   = d_in[17];
  const void* aang  = d_in[18];
  const void* Wd    = d_in[19];
  const void* bd    = d_in[20];
  const void* lsc   = d_in[21];
  float* ws = (float*)d_ws;

  VInit vi = make_vinit();

  hipLaunchKernelGGL(detect_kernel, dim3(1), dim3(64), 0, stream,
      (const uint32_t*)Wg1, ws);
  hipLaunchKernelGGL(prep_kernel, dim3(B_), dim3(256), 0, stream,
      xy, Wg1, bg1, bg2w, bg2b, Wa1, ba1, Wa2, ba2, apair, ageom, aang, lsc, ws, vi);
  hipLaunchKernelGGL(fold_kernel, dim3(1536), dim3(256), 0, stream, feats, ws);
  hipLaunchKernelGGL(proj_kernel, dim3(7, 64), dim3(256), 0, stream,
      Wq, Wk, Wpi, bpi, Wpj, bpj, Wd, bd, ws);
  hipLaunchKernelGGL(score_kernel, dim3(16, 16, B_), dim3(256), 0, stream,
      xy, ws, d_out);
}

// Round 4
// 182.891 us; speedup vs baseline: 1.7032x; 1.1001x over previous
//
#include <hip/hip_runtime.h>
#include <hip/hip_bf16.h>
#include <stdint.h>
#include <string.h>
#include <math.h>

// Problem constants
#define B_ 8
#define N_ 512
#define C_ 384
#define HR_ 192          // H*R = 6*32
#define PH_ 16           // PAIR_HIDDEN
#define HEAD_SCALE_ 0.17677669529663687f
#define QK2W_ 224        // packed row: 192 Q/K | 16 pair | 16 zero  (7 x K=32)
#define WTC_ 448         // WT col count: 192 Q | 192 K | 16 pi | 16 pj | 1 d | 31 pad

// Workspace layout (float offsets).
// X, WT, Q2, K2 are hi/lo bf16 pairs: the 3-term split
// S = Ahi.Bhi + Ahi.Blo + Alo.Bhi reconstructs the f32 bilinear form to
// ~2^-18 relative (lo.lo dropped) — verified within tolerance in round 3.
#define OFF_XH   0                           // 4096x384 bf16 = 786432 floats
#define OFF_XL   786432
#define OFF_WTH  1572864                     // 448x384 bf16 = 86016 floats
#define OFF_WTL  1658880
#define OFF_Q2   1744896                     // 8*512*224 bf16 = 458752 floats
#define OFF_Q2L  2203648
#define OFF_K2   2662400
#define OFF_K2L  3121152
#define OFF_D    3579904                     // 4096 floats
#define OFF_CS   3584000                     // 16
#define OFF_W    3584016                     // 768
#define OFF_FLAG (OFF_W + 700)               // int: 1 = inputs are bf16, 0 = f32
#define WS_FLOATS (OFF_W + 768)

struct VInit { float v[16]; };

typedef __attribute__((ext_vector_type(8))) short short8v;
typedef __attribute__((ext_vector_type(4))) float f32x4;

__device__ __forceinline__ float cvt(ushort u) {
  union { uint32_t i; float f; } x; x.i = ((uint32_t)u) << 16; return x.f;
}
__device__ __forceinline__ float cvt(float f) { return f; }

__device__ __forceinline__ ushort f2bf(float f) {
  __hip_bfloat16 h = __float2bfloat16(f);
  union { __hip_bfloat16 b; ushort u; } x; x.b = h; return x.u;
}

__device__ __forceinline__ float4 ld4v(const ushort* p) {
  ushort4 u = *(const ushort4*)p;
  return make_float4(cvt(u.x), cvt(u.y), cvt(u.z), cvt(u.w));
}
__device__ __forceinline__ float4 ld4v(const float* p) { return *(const float4*)p; }

__device__ __forceinline__ void split_bf(float v, ushort& hi, ushort& lo) {
  hi = f2bf(v);
  lo = f2bf(v - cvt(hi));
}

// ---------------------------------------------------------------------------
// Kernel 0: dtype detection. If Wg1 holds bf16, the low ushort of each dword
// decodes to a sane-magnitude bf16 (N(0,0.3) weights). If it holds f32, the
// low 16 bits are uniform mantissa bits (sane-decode prob ~10%). 128 dwords
// are valid to read under both layouts (512 B <= min(768, 1536) B).
// ---------------------------------------------------------------------------
__global__ void detect_kernel(const uint32_t* __restrict__ wg1, float* __restrict__ ws) {
  if (threadIdx.x == 0 && blockIdx.x == 0) {
    int cnt = 0;
    for (int i = 0; i < 128; ++i) {
      uint32_t d = wg1[i];
      float v = cvt((ushort)(d & 0xFFFFu));
      float av = fabsf(v);
      if (av == 0.0f || (av >= 9.5367431640625e-07f && av <= 32.0f)) ++cnt;
    }
    *(int*)(ws + OFF_FLAG) = (cnt >= 64) ? 1 : 0;
  }
}

// ---------------------------------------------------------------------------
// Weight tables (transposed for uniform scalar loads in score kernel)
// ---------------------------------------------------------------------------
template <typename T>
__device__ void build_tables(const T* Wg1, const T* bg1, const T* Wg2, const T* bg2,
                             const T* Wa1, const T* ba1, const T* Wa2, const T* ba2,
                             const T* apair, const T* ageom, const T* aang, const T* lsc,
                             float* ws, int tid) {
  for (int j = tid; j < 32; j += 256) {
    float* wj = ws + OFF_W + j*16;
    #pragma unroll
    for (int i = 0; i < 12; ++i) wj[i] = cvt(Wg1[i*32 + j]);
    wj[12] = cvt(bg1[j]);
    wj[13] = cvt(Wg2[j]);
    wj[14] = 0.f; wj[15] = 0.f;
  }
  for (int j = tid; j < 16; j += 256) {
    float* wj = ws + OFF_W + 512 + j*8;
    #pragma unroll
    for (int i = 0; i < 6; ++i) wj[i] = cvt(Wa1[i*16 + j]);
    wj[6] = cvt(ba1[j]);
    wj[7] = cvt(Wa2[j]);
  }
  if (tid == 0) {
    ws[OFF_W + 640] = cvt(bg2[0]);
    ws[OFF_W + 641] = cvt(ba2[0]);
    ws[OFF_W + 642] = fmaxf(cvt(apair[0]), 0.f);
    ws[OFF_W + 643] = fmaxf(cvt(ageom[0]), 0.f);
    ws[OFF_W + 644] = fmaxf(cvt(aang[0]), 0.f);
    ws[OFF_W + 645] = fmaxf(cvt(lsc[0]), 0.01f);
  }
}

// ---------------------------------------------------------------------------
// Kernel A: per-batch principal orientation (power iteration) + weight tables
// ---------------------------------------------------------------------------
__global__ __launch_bounds__(256) void prep_kernel(
    const void* __restrict__ xy,
    const void* __restrict__ Wg1, const void* __restrict__ bg1,
    const void* __restrict__ Wg2, const void* __restrict__ bg2,
    const void* __restrict__ Wa1, const void* __restrict__ ba1,
    const void* __restrict__ Wa2, const void* __restrict__ ba2,
    const void* __restrict__ apair, const void* __restrict__ ageom,
    const void* __restrict__ aang, const void* __restrict__ lsc,
    float* __restrict__ ws, VInit vi)
{
  const int b = blockIdx.x, tid = threadIdx.x;
  const int bf = *(volatile const int*)(ws + OFF_FLAG);
  __shared__ float sxy[N_*2];
  __shared__ float red[256][4];

  if (bf) {
    const ushort* p = (const ushort*)xy + b*N_*2;
    for (int i = tid; i < N_*2; i += 256) sxy[i] = cvt(p[i]);
  } else {
    const float* p = (const float*)xy + b*N_*2;
    for (int i = tid; i < N_*2; i += 256) sxy[i] = p[i];
  }
  __syncthreads();

  // pass 1: mean
  float sy = 0.f, sx = 0.f;
  for (int i = tid; i < N_; i += 256) { sy += sxy[2*i]; sx += sxy[2*i+1]; }
  red[tid][0] = sy; red[tid][1] = sx;
  __syncthreads();
  for (int s = 128; s > 0; s >>= 1) {
    if (tid < s) { red[tid][0] += red[tid+s][0]; red[tid][1] += red[tid+s][1]; }
    __syncthreads();
  }
  const float my = red[0][0] / 512.0f;
  const float mx = red[0][1] / 512.0f;
  __syncthreads();

  // pass 2: covariance
  float c00 = 0.f, c01 = 0.f, c11 = 0.f;
  for (int i = tid; i < N_; i += 256) {
    float y = sxy[2*i] - my;
    float x = sxy[2*i+1] - mx;
    c00 += y*y; c01 += y*x; c11 += x*x;
  }
  red[tid][0] = c00; red[tid][1] = c01; red[tid][2] = c11;
  __syncthreads();
  for (int s = 128; s > 0; s >>= 1) {
    if (tid < s) {
      red[tid][0] += red[tid+s][0];
      red[tid][1] += red[tid+s][1];
      red[tid][2] += red[tid+s][2];
    }
    __syncthreads();
  }
  if (tid == 0) {
    float C00 = red[0][0] / 512.0f, C01 = red[0][1] / 512.0f, C11 = red[0][2] / 512.0f;
    float v0 = vi.v[2*b], v1 = vi.v[2*b + 1];
    float nr = sqrtf(v0*v0 + v1*v1) + 1e-8f; v0 /= nr; v1 /= nr;
    for (int it = 0; it < 5; ++it) {
      float w0 = C00*v0 + C01*v1;
      float w1 = C01*v0 + C11*v1;
      nr = sqrtf(w0*w0 + w1*w1) + 1e-8f;
      v0 = w0/nr; v1 = w1/nr;
    }
    float h = sqrtf(v0*v0 + v1*v1);
    ws[OFF_CS + 2*b + 0] = v0 / h;   // cos(theta0)
    ws[OFF_CS + 2*b + 1] = v1 / h;   // sin(theta0)
  }

  if (b == 0) {
    if (bf) build_tables((const ushort*)Wg1, (const ushort*)bg1, (const ushort*)Wg2, (const ushort*)bg2,
                         (const ushort*)Wa1, (const ushort*)ba1, (const ushort*)Wa2, (const ushort*)ba2,
                         (const ushort*)apair, (const ushort*)ageom, (const ushort*)aang, (const ushort*)lsc,
                         ws, tid);
    else    build_tables((const float*)Wg1, (const float*)bg1, (const float*)Wg2, (const float*)bg2,
                         (const float*)Wa1, (const float*)ba1, (const float*)Wa2, (const float*)ba2,
                         (const float*)apair, (const float*)ageom, (const float*)aang, (const float*)lsc,
                         ws, tid);
  }
}

// ---------------------------------------------------------------------------
// Kernel B: fold vertices -> X (hi/lo bf16 split) + weight-transpose split.
//   Blocks [0,1536): X[bn][c] = 0.5*(feats[.,1+2n,.]+feats[.,2+2n,.]), split
//   into XH/XL bf16 arrays (fragment-ready row-major [row][k]).
//   Blocks [1536,2208): WT[col][k] hi/lo, col map:
//     0..191 HEAD_SCALE*Wq | 192..383 Wk | 384..399 Wpi | 400..415 Wpj |
//     416 Wd | 417..447 zero.
// ---------------------------------------------------------------------------
template <typename T>
__device__ __forceinline__ void fold_body(const T* feats, float* ws, int idx) {
  const int c4 = idx % 96;
  const int bn = idx / 96;
  const int n = bn & (N_ - 1), b = bn >> 9;
  const T* r1 = feats + ((size_t)(b*(2*N_+1) + 1 + 2*n))*C_ + c4*4;
  float4 a = ld4v(r1);
  float4 c = ld4v(r1 + C_);
  float4 o;
  o.x = 0.5f*(a.x + c.x); o.y = 0.5f*(a.y + c.y);
  o.z = 0.5f*(a.z + c.z); o.w = 0.5f*(a.w + c.w);
  ushort4 oh, ol;
  split_bf(o.x, oh.x, ol.x);
  split_bf(o.y, oh.y, ol.y);
  split_bf(o.z, oh.z, ol.z);
  split_bf(o.w, oh.w, ol.w);
  const size_t off = (size_t)bn*C_ + c4*4;
  *(ushort4*)((ushort*)(ws + OFF_XH) + off) = oh;
  *(ushort4*)((ushort*)(ws + OFF_XL) + off) = ol;
}

template <typename T>
__device__ __forceinline__ void wsplit_body(const T* Wq, const T* Wk,
                                            const T* Wpi, const T* Wpj,
                                            const T* Wd, float* ws, int gidx) {
  const int col = gidx / C_;
  const int k   = gidx - col*C_;
  float v;
  if      (col < 192) v = HEAD_SCALE_ * cvt(Wq[k*HR_ + col]);
  else if (col < 384) v = cvt(Wk[k*HR_ + (col - 192)]);
  else if (col < 400) v = cvt(Wpi[k*PH_ + (col - 384)]);
  else if (col < 416) v = cvt(Wpj[k*PH_ + (col - 400)]);
  else if (col == 416) v = cvt(Wd[k]);
  else v = 0.f;
  ushort hi, lo; split_bf(v, hi, lo);
  ((ushort*)(ws + OFF_WTH))[gidx] = hi;
  ((ushort*)(ws + OFF_WTL))[gidx] = lo;
}

__global__ __launch_bounds__(256) void fold_kernel(
    const void* __restrict__ feats,
    const void* __restrict__ Wq, const void* __restrict__ Wk,
    const void* __restrict__ Wpi, const void* __restrict__ Wpj,
    const void* __restrict__ Wd,
    float* __restrict__ ws)
{
  const int bid = blockIdx.x;
  const int bf = *(volatile const int*)(ws + OFF_FLAG);
  if (bid < 1536) {
    const int idx = bid * 256 + threadIdx.x;
    if (bf) fold_body((const ushort*)feats, ws, idx);
    else    fold_body((const float*)feats, ws, idx);
  } else {
    const int gidx = (bid - 1536) * 256 + threadIdx.x;   // < 448*384
    if (bf) wsplit_body((const ushort*)Wq, (const ushort*)Wk, (const ushort*)Wpi,
                        (const ushort*)Wpj, (const ushort*)Wd, ws, gidx);
    else    wsplit_body((const float*)Wq, (const float*)Wk, (const float*)Wpi,
                        (const float*)Wpj, (const float*)Wd, ws, gidx);
  }
}

// ---------------------------------------------------------------------------
// Kernel C: MFMA projection GEMM. X(4096x384) @ WT^T(384x448) via 3-term
// hi/lo split. 1 wave/block, 32x32 output tile, grid (14 col, 128 row).
// No LDS: A-frags from XH/XL rows, B-frags from WT rows (both contiguous
// 16B/lane). Epilogue: split-bf16 pack into Q2/K2 (+bias/relu/ap for pair
// cols, d col, zero-pad).
// ---------------------------------------------------------------------------
#define MFA(a,b,c) __builtin_amdgcn_mfma_f32_16x16x32_bf16(a, b, c, 0, 0, 0)

__global__ __launch_bounds__(64) void proj_kernel(
    const void* __restrict__ bpi, const void* __restrict__ bpj,
    const void* __restrict__ bd,  float* __restrict__ ws)
{
  const int ct = blockIdx.x;       // 0..13 -> cols ct*32
  const int rt = blockIdx.y;       // 0..127 -> rows rt*32
  const int l  = threadIdx.x;
  const int lr = l & 15, lk = l >> 4;
  const int row0 = rt * 32, colg0 = ct * 32;
  const int bf = *(volatile const int*)(ws + OFF_FLAG);

  const ushort* xh  = (const ushort*)(ws + OFF_XH);
  const ushort* xl  = (const ushort*)(ws + OFF_XL);
  const ushort* wth = (const ushort*)(ws + OFF_WTH);
  const ushort* wtl = (const ushort*)(ws + OFF_WTL);

  const size_t a0 = (size_t)(row0 + lr) * C_ + lk*8;
  const size_t a1 = a0 + (size_t)16 * C_;
  const size_t b0 = (size_t)(colg0 + lr) * C_ + lk*8;
  const size_t b1 = b0 + (size_t)16 * C_;

  f32x4 acc00 = {0,0,0,0}, acc01 = {0,0,0,0}, acc10 = {0,0,0,0}, acc11 = {0,0,0,0};

  // prologue prefetch
  short8v ah0 = *(const short8v*)(xh + a0);
  short8v ah1 = *(const short8v*)(xh + a1);
  short8v al0 = *(const short8v*)(xl + a0);
  short8v al1 = *(const short8v*)(xl + a1);
  short8v bh0 = *(const short8v*)(wth + b0);
  short8v bh1 = *(const short8v*)(wth + b1);
  short8v bl0 = *(const short8v*)(wtl + b0);
  short8v bl1 = *(const short8v*)(wtl + b1);

  for (int ks = 0; ks < 12; ++ks) {
    short8v nah0, nah1, nal0, nal1, nbh0, nbh1, nbl0, nbl1;
    if (ks < 11) {
      const int o = (ks + 1) * 32;
      nah0 = *(const short8v*)(xh + a0 + o);
      nah1 = *(const short8v*)(xh + a1 + o);
      nal0 = *(const short8v*)(xl + a0 + o);
      nal1 = *(const short8v*)(xl + a1 + o);
      nbh0 = *(const short8v*)(wth + b0 + o);
      nbh1 = *(const short8v*)(wth + b1 + o);
      nbl0 = *(const short8v*)(wtl + b0 + o);
      nbl1 = *(const short8v*)(wtl + b1 + o);
    }
    acc00 = MFA(ah0, bh0, acc00);
    acc00 = MFA(ah0, bl0, acc00);
    acc00 = MFA(al0, bh0, acc00);
    acc01 = MFA(ah0, bh1, acc01);
    acc01 = MFA(ah0, bl1, acc01);
    acc01 = MFA(al0, bh1, acc01);
    acc10 = MFA(ah1, bh0, acc10);
    acc10 = MFA(ah1, bl0, acc10);
    acc10 = MFA(al1, bh0, acc10);
    acc11 = MFA(ah1, bh1, acc11);
    acc11 = MFA(ah1, bl1, acc11);
    acc11 = MFA(al1, bh1, acc11);
    if (ks < 11) {
      ah0 = nah0; ah1 = nah1; al0 = nal0; al1 = nal1;
      bh0 = nbh0; bh1 = nbh1; bl0 = nbl0; bl1 = nbl1;
    }
  }

  // epilogue
  ushort* q2h = (ushort*)(ws + OFF_Q2);
  ushort* q2l = (ushort*)(ws + OFF_Q2L);
  ushort* k2h = (ushort*)(ws + OFF_K2);
  ushort* k2l = (ushort*)(ws + OFF_K2L);
  const float ap  = ws[OFF_W + 642];
  const float bdv = bf ? cvt(((const ushort*)bd)[0]) : ((const float*)bd)[0];

  #pragma unroll
  for (int i = 0; i < 2; ++i) {
    #pragma unroll
    for (int j = 0; j < 2; ++j) {
      const f32x4 A = (i == 0) ? (j == 0 ? acc00 : acc01) : (j == 0 ? acc10 : acc11);
      const int gcol = colg0 + j*16 + lr;
      // per-column epilogue params (uniform over r)
      float bias = 0.f, post = 1.f; int mode;  // 0: plain Q, 1: plain K, 2: relu Q, 3: relu K, 4: d, 5: skip
      int dcol = 0;
      if (gcol < 192)      { mode = 0; dcol = gcol; }
      else if (gcol < 384) { mode = 1; dcol = gcol - 192; }
      else if (gcol < 400) {
        mode = 2; dcol = 192 + (gcol - 384); post = ap;
        bias = bf ? cvt(((const ushort*)bpi)[gcol - 384]) : ((const float*)bpi)[gcol - 384];
      }
      else if (gcol < 416) {
        mode = 3; dcol = 192 + (gcol - 400);
        bias = bf ? cvt(((const ushort*)bpj)[gcol - 400]) : ((const float*)bpj)[gcol - 400];
      }
      else if (gcol == 416) mode = 4;
      else mode = 5;

      #pragma unroll
      for (int r = 0; r < 4; ++r) {
        const int grow = row0 + i*16 + lk*4 + r;
        float v = A[r];
        if (mode == 0) {
          ushort hi, lo; split_bf(v, hi, lo);
          q2h[(size_t)grow*QK2W_ + dcol] = hi;
          q2l[(size_t)grow*QK2W_ + dcol] = lo;
        } else if (mode == 1) {
          ushort hi, lo; split_bf(v, hi, lo);
          k2h[(size_t)grow*QK2W_ + dcol] = hi;
          k2l[(size_t)grow*QK2W_ + dcol] = lo;
        } else if (mode == 2) {
          float t = post * fmaxf(v + bias, 0.f);
          ushort hi, lo; split_bf(t, hi, lo);
          q2h[(size_t)grow*QK2W_ + dcol] = hi;
          q2l[(size_t)grow*QK2W_ + dcol] = lo;
        } else if (mode == 3) {
          float t = fmaxf(v + bias, 0.f);
          ushort hi, lo; split_bf(t, hi, lo);
          k2h[(size_t)grow*QK2W_ + dcol] = hi;
          k2l[(size_t)grow*QK2W_ + dcol] = lo;
        } else if (mode == 4) {
          ws[OFF_D + grow] = v + bdv;
        }
      }
    }
  }

  // zero Q2/K2 pad cols 208..223 (hi+lo): handled by the otherwise-idle ct==13
  if (ct == 13) {
    const int rr = l >> 1, h = l & 1;        // 32 rows x 2 col-halves
    const size_t off = (size_t)(row0 + rr)*QK2W_ + 208 + h*8;
    const uint4 z = make_uint4(0,0,0,0);     // 8 ushorts
    *(uint4*)(q2h + off) = z;
    *(uint4*)(q2l + off) = z;
    *(uint4*)(k2h + off) = z;
    *(uint4*)(k2l + off) = z;
  }
}

// ---------------------------------------------------------------------------
// Kernel D (unified): MFMA score assembly. 4 waves/block, each wave a 16x16
// quadrant of the 32x32 output tile. A/B fragments load directly from global
// (contiguous 16B per lane) — no LDS staging. 3-term hi/lo split reconstructs
// the f32 bilinear part: acc = HEAD_SCALE*QK^T + alpha_pair*a_i.b_j.
// MLPs stay in f32 VALU. Only xy load + out store branch on dtype.
// ---------------------------------------------------------------------------
__global__ __launch_bounds__(256) void score_kernel(
    const void* __restrict__ xy, const float* __restrict__ ws,
    void* __restrict__ out)
{
  const int bf = *(volatile const int*)(ws + OFF_FLAG);
  const int b  = blockIdx.z;
  const int n0 = blockIdx.y * 32, m0 = blockIdx.x * 32;
  const int tid = threadIdx.x;

  __shared__ float xyn[32][2], xym[32][2], dn[32];
  if (tid < 32) {
    if (bf) {
      const ushort* p = (const ushort*)xy;
      xyn[tid][0] = cvt(p[((b*N_) + n0 + tid)*2 + 0]);
      xyn[tid][1] = cvt(p[((b*N_) + n0 + tid)*2 + 1]);
      xym[tid][0] = cvt(p[((b*N_) + m0 + tid)*2 + 0]);
      xym[tid][1] = cvt(p[((b*N_) + m0 + tid)*2 + 1]);
    } else {
      const float* p = (const float*)xy;
      xyn[tid][0] = p[((b*N_) + n0 + tid)*2 + 0];
      xyn[tid][1] = p[((b*N_) + n0 + tid)*2 + 1];
      xym[tid][0] = p[((b*N_) + m0 + tid)*2 + 0];
      xym[tid][1] = p[((b*N_) + m0 + tid)*2 + 1];
    }
    dn[tid] = ws[OFF_D + b*N_ + n0 + tid];
  }
  __syncthreads();

  const int w  = tid >> 6, l = tid & 63;
  const int wr = w >> 1, wc = w & 1;      // wave quadrant (2x2 of 16x16)
  const int lr = l & 15, lk = l >> 4;     // frag row/col, k-group

  const size_t qoff = ((size_t)(b*N_) + n0 + wr*16 + lr) * QK2W_ + lk*8;
  const size_t koff = ((size_t)(b*N_) + m0 + wc*16 + lr) * QK2W_ + lk*8;
  const ushort* qh = (const ushort*)(ws + OFF_Q2)  + qoff;
  const ushort* ql = (const ushort*)(ws + OFF_Q2L) + qoff;
  const ushort* kh = (const ushort*)(ws + OFF_K2)  + koff;
  const ushort* kl = (const ushort*)(ws + OFF_K2L) + koff;

  f32x4 acc = {0.f, 0.f, 0.f, 0.f};
  #pragma unroll
  for (int kc = 0; kc < 7; ++kc) {
    short8v ah = *(const short8v*)(qh + kc*32);
    short8v al = *(const short8v*)(ql + kc*32);
    short8v bh = *(const short8v*)(kh + kc*32);
    short8v bl = *(const short8v*)(kl + kc*32);
    acc = __builtin_amdgcn_mfma_f32_16x16x32_bf16(ah, bh, acc, 0, 0, 0);
    acc = __builtin_amdgcn_mfma_f32_16x16x32_bf16(ah, bl, acc, 0, 0, 0);
    acc = __builtin_amdgcn_mfma_f32_16x16x32_bf16(al, bh, acc, 0, 0, 0);
  }
  // lane l, reg r -> row (wr*16 + lk*4 + r), col (wc*16 + lr)   [m89 layout]

  const float c0 = ws[OFF_CS + 2*b], s0 = ws[OFF_CS + 2*b + 1];
  const float* wsm = ws + OFF_W;
  const float bg2v = wsm[640], ba2v = wsm[641];
  const float ag = wsm[643], aa = wsm[644], ls = wsm[645];

  const int ml = wc*16 + lr;              // col within 32-tile (fixed per lane)
  const float ym = xym[ml][0], xm = xym[ml][1];

  const float STEP  = 1.41421354f / 7.0f;
  const float GAMMA = 1.0f / (2.0f*STEP*STEP + 1e-8f);
  float C1[4], S1[4], C2[4], S2[4], C4v[4], S4[4], DY[4], DX[4], PHI[4][8];
  #pragma unroll
  for (int r = 0; r < 4; ++r) {
    const int nl_ = wr*16 + lk*4 + r;     // row within 32-tile
    float dy = xyn[nl_][0] - ym, dx = xyn[nl_][1] - xm;
    DY[r] = dy; DX[r] = dx;
    float h2 = fmaf(dx, dx, dy*dy);
    float rr = sqrtf(h2 + 1e-8f);
    float ct, st;
    if (h2 > 0.f) { float ih = 1.0f / sqrtf(h2); ct = dx*ih; st = dy*ih; }
    else          { ct = 1.f; st = 0.f; }             // atan2(0,0)=0
    float c1 = ct*c0 + st*s0;                         // cos(theta - theta0)
    float s1 = st*c0 - ct*s0;                         // sin(theta - theta0)
    C1[r] = c1; S1[r] = s1;
    float c2 = c1*c1 - s1*s1, s2 = 2.f*c1*s1;
    C2[r] = c2; S2[r] = s2;
    C4v[r] = c2*c2 - s2*s2; S4[r] = 2.f*c2*s2;
    #pragma unroll
    for (int k = 0; k < 8; ++k) {
      float d = rr - (float)k * STEP;
      PHI[r][k] = __expf(-GAMMA * d * d);
    }
  }

  // G MLP: 12 -> 32 -> 1 (weights via uniform scalar loads)
  float g[4] = {0,0,0,0};
  #pragma unroll 4
  for (int j = 0; j < 32; ++j) {
    const float* wj = wsm + j*16;
    #pragma unroll
    for (int r = 0; r < 4; ++r) {
      float h = fmaf(DY[r], wj[0], fmaf(DX[r], wj[1], wj[12]));
      #pragma unroll
      for (int k = 0; k < 8; ++k) h = fmaf(PHI[r][k], wj[2+k], h);
      h = fmaf(C1[r], wj[10], fmaf(S1[r], wj[11], h));
      g[r] = fmaf(fmaxf(h, 0.f), wj[13], g[r]);
    }
  }

  // angle MLP: 6 -> 16 -> 1
  float hb[4] = {0,0,0,0};
  #pragma unroll 4
  for (int j = 0; j < 16; ++j) {
    const float* wj = wsm + 512 + j*8;
    #pragma unroll
    for (int r = 0; r < 4; ++r) {
      float h = fmaf(C1[r],  wj[0], fmaf(S1[r], wj[1], wj[6]));
      h = fmaf(C2[r],  wj[2], fmaf(S2[r], wj[3], h));
      h = fmaf(C4v[r], wj[4], fmaf(S4[r], wj[5], h));
      hb[r] = fmaf(fmaxf(h, 0.f), wj[7], hb[r]);
    }
  }

  const int m_g = m0 + ml;
  #pragma unroll
  for (int r = 0; r < 4; ++r) {
    const int nl_ = wr*16 + lk*4 + r;
    const int n_g = n0 + nl_;
    float S = acc[r] + ag*(g[r] + bg2v) + aa*(hb[r] + ba2v);
    if (n_g == m_g) S += dn[nl_];
    S *= ls;
    const size_t oi = ((size_t)(b*N_) + n_g)*N_ + m_g;
    if (bf) ((__hip_bfloat16*)out)[oi] = __float2bfloat16(S);
    else    ((float*)out)[oi] = S;
  }
}

// ---------------------------------------------------------------------------
// Host: replicate jax.random.normal(key(42), (8,2,1)) — threefry2x32
// (partitionable mode) + XLA/Giles f32 erfinv.
// ---------------------------------------------------------------------------
static inline uint32_t rotl32(uint32_t x, int d) { return (x << d) | (x >> (32 - d)); }

static void threefry2x32_host(uint32_t k0, uint32_t k1, uint32_t& x0, uint32_t& x1) {
  const uint32_t ks0 = k0, ks1 = k1, ks2 = k0 ^ k1 ^ 0x1BD11BDAu;
  static const int R[2][4] = {{13,15,26,6},{17,29,16,24}};
  x0 += ks0; x1 += ks1;
  const uint32_t ks[3] = {ks0, ks1, ks2};
  for (int i = 0; i < 5; ++i) {
    const int* r = R[i & 1];
    for (int j = 0; j < 4; ++j) { x0 += x1; x1 = rotl32(x1, r[j]); x1 ^= x0; }
    x0 += ks[(i + 1) % 3];
    x1 += ks[(i + 2) % 3] + (uint32_t)(i + 1);
  }
}

static float erfinv_host(float x) {
  float w = -log1pf(-x * x);
  float p;
  if (w < 5.0f) {
    w = w - 2.5f;
    p = 2.81022636e-08f;
    p = fmaf(p, w, 3.43273939e-07f);
    p = fmaf(p, w, -3.5233877e-06f);
    p = fmaf(p, w, -4.39150654e-06f);
    p = fmaf(p, w, 0.00021858087f);
    p = fmaf(p, w, -0.00125372503f);
    p = fmaf(p, w, -0.00417768164f);
    p = fmaf(p, w, 0.246640727f);
    p = fmaf(p, w, 1.50140941f);
  } else {
    w = sqrtf(w) - 3.0f;
    p = -0.000200214257f;
    p = fmaf(p, w, 0.000100950558f);
    p = fmaf(p, w, 0.00134934322f);
    p = fmaf(p, w, -0.00367342844f);
    p = fmaf(p, w, 0.00573950773f);
    p = fmaf(p, w, -0.0076224613f);
    p = fmaf(p, w, 0.00943887047f);
    p = fmaf(p, w, 1.00167406f);
    p = fmaf(p, w, 2.83297682f);
  }
  return p * x;
}

static VInit make_vinit() {
  VInit vi;
  for (int i = 0; i < 16; ++i) {
    uint32_t o0 = 0u, o1 = (uint32_t)i;
    threefry2x32_host(0u, 42u, o0, o1);
    uint32_t bits = o0 ^ o1;
    uint32_t fb = (bits >> 9) | 0x3f800000u;
    float f; memcpy(&f, &fb, 4); f -= 1.0f;
    const float lo = -0.99999994f;
    float u = f * 2.0f + lo;
    if (u < lo) u = lo;
    vi.v[i] = 1.41421354f * erfinv_host(u);
  }
  return vi;
}

// ---------------------------------------------------------------------------
extern "C" void kernel_launch(void* const* d_in, const int* in_sizes, int n_in,
                              void* d_out, int out_size, void* d_ws, size_t ws_size,
                              hipStream_t stream) {
  (void)in_sizes; (void)n_in; (void)out_size;
  if (ws_size < (size_t)WS_FLOATS * sizeof(float)) return;

  const void* feats = d_in[0];
  const void* xy    = d_in[1];
  const void* Wq    = d_in[2];
  const void* Wk    = d_in[3];
  const void* Wpi   = d_in[4];
  const void* bpi   = d_in[5];
  const void* Wpj   = d_in[6];
  const void* bpj   = d_in[7];
  const void* apair = d_in[8];
  const void* Wg1   = d_in[9];
  const void* bg1   = d_in[10];
  const void* bg2w  = d_in[11];  // Wg2
  const void* bg2b  = d_in[12];  // bg2
  const void* ageom = d_in[13];
  const void* Wa1   = d_in[14];
  const void* ba1   = d_in[15];
  const void* Wa2   = d_in[16];
  const void* ba2   = d_in[17];
  const void* aang  = d_in[18];
  const void* Wd    = d_in[19];
  const void* bd    = d_in[20];
  const void* lsc   = d_in[21];
  float* ws = (float*)d_ws;

  VInit vi = make_vinit();

  hipLaunchKernelGGL(detect_kernel, dim3(1), dim3(64), 0, stream,
      (const uint32_t*)Wg1, ws);
  hipLaunchKernelGGL(prep_kernel, dim3(B_), dim3(256), 0, stream,
      xy, Wg1, bg1, bg2w, bg2b, Wa1, ba1, Wa2, ba2, apair, ageom, aang, lsc, ws, vi);
  hipLaunchKernelGGL(fold_kernel, dim3(2208), dim3(256), 0, stream,
      feats, Wq, Wk, Wpi, Wpj, Wd, ws);
  hipLaunchKernelGGL(proj_kernel, dim3(14, 128), dim3(64), 0, stream,
      bpi, bpj, bd, ws);
  hipLaunchKernelGGL(score_kernel, dim3(16, 16, B_), dim3(256), 0, stream,
      xy, ws, d_out);
}